// Round 14
// baseline (298.700 us; speedup 1.0000x reference)
//
#include <hip/hip_runtime.h>
#include <hip/hip_bf16.h>

typedef __attribute__((ext_vector_type(4))) float f32x4;
typedef __attribute__((ext_vector_type(8))) short bf16x8;
typedef __attribute__((ext_vector_type(4))) unsigned short u16x4;
typedef __attribute__((ext_vector_type(8))) unsigned short u16x8;

#define QCAP 8256  // compact q buffer row capacity
#define QSTR ((size_t)QCAP * 512)

__device__ __forceinline__ unsigned short f2bf(float f) {
  unsigned int u = __builtin_bit_cast(unsigned int, f);
  unsigned int r = (u + 0x7FFFu + ((u >> 16) & 1u)) >> 16;
  return (unsigned short)r;
}
__device__ __forceinline__ float bf2f(unsigned short h) {
  unsigned int u = ((unsigned int)h) << 16;
  return __builtin_bit_cast(float, u);
}

__device__ __forceinline__ void gload_lds16(const void* g, void* l) {
  __builtin_amdgcn_global_load_lds(
      (__attribute__((address_space(1))) unsigned int*)g,
      (__attribute__((address_space(3))) unsigned int*)l, 16, 0, 0);
}

// ---------- fused: 3 weight transposes + latent bf16 convert (1 launch) ----------
// bid [0,2048): W_q 4096x512; [2048,4096): W_vk 2048x1024;
// [4096,6144): W_out 512x4096; [6144,6912): latent -> latbf (2048 elems/block)
__global__ __launch_bounds__(256) void transpose_split3(
    const float* __restrict__ Wq, const float* __restrict__ Wvk,
    const float* __restrict__ Wo, const float* __restrict__ latent,
    unsigned short* __restrict__ QTh, unsigned short* __restrict__ QTl,
    unsigned short* __restrict__ VKh, unsigned short* __restrict__ VKl,
    unsigned short* __restrict__ OTh, unsigned short* __restrict__ OTl,
    unsigned short* __restrict__ latbf) {
  int bid = blockIdx.x;
  if (bid >= 6144) {  // latent convert
    long i = ((long)(bid - 6144) * 256 + threadIdx.x) * 8;
    f32x4 a = *(const f32x4*)(latent + i);
    f32x4 b = *(const f32x4*)(latent + i + 4);
    u16x8 o;
#pragma unroll
    for (int j = 0; j < 4; ++j) o[j] = f2bf(a[j]);
#pragma unroll
    for (int j = 0; j < 4; ++j) o[4 + j] = f2bf(b[j]);
    *(u16x8*)(latbf + i) = o;
    return;
  }
  __shared__ float tile[32][33];
  const float* W;
  unsigned short *Th, *Tl;
  int K, N, nbx, b;
  if (bid < 2048) {
    W = Wq; Th = QTh; Tl = QTl; K = 4096; N = 512; nbx = 16; b = bid;
  } else if (bid < 4096) {
    W = Wvk; Th = VKh; Tl = VKl; K = 2048; N = 1024; nbx = 32; b = bid - 2048;
  } else {
    W = Wo; Th = OTh; Tl = OTl; K = 512; N = 4096; nbx = 128; b = bid - 4096;
  }
  int n0 = (b % nbx) * 32, k0 = (b / nbx) * 32;
  int tx = threadIdx.x & 31, ty = threadIdx.x >> 5;
#pragma unroll
  for (int r = 0; r < 4; ++r)
    tile[ty + 8 * r][tx] = W[(size_t)(k0 + ty + 8 * r) * N + n0 + tx];
  __syncthreads();
#pragma unroll
  for (int r = 0; r < 4; ++r) {
    float f = tile[tx][ty + 8 * r];
    unsigned short hi = f2bf(f);
    unsigned short lo = f2bf(f - bf2f(hi));
    size_t o = (size_t)(n0 + ty + 8 * r) * K + k0 + tx;
    Th[o] = hi;
    Tl[o] = lo;
  }
}

// ---------- gather rows by (b, t); also collect masked rows ----------
__global__ __launch_bounds__(256) void gather_rows(const int* __restrict__ mask,
                                                   int* __restrict__ cnt,
                                                   int* __restrict__ idx,
                                                   int* __restrict__ mcnt,
                                                   int* __restrict__ mlist) {
  int g = blockIdx.x * 256 + threadIdx.x;
  int m = mask[g];
  if (m > 0) {
    int bt = (g >> 11) * 3 + m - 1;
    int p = atomicAdd(&cnt[bt], 1);
    idx[bt * 2048 + p] = g;
  } else {
    int p = atomicAdd(mcnt, 1);
    mlist[p] = g;
  }
}

// ---------- scan (local) + build bucket-major compact list ----------
__global__ __launch_bounds__(256) void scan_build(const int* __restrict__ cnt,
                                                  int* __restrict__ offs,
                                                  const int* __restrict__ idx,
                                                  int* __restrict__ glob) {
  __shared__ int so[13];
  if (threadIdx.x == 0) {
    int s = 0;
#pragma unroll
    for (int i = 0; i < 12; ++i) {
      so[i] = s;
      s += cnt[i];
    }
    so[12] = s;
    if (blockIdx.x == 0)
#pragma unroll
      for (int i = 0; i < 13; ++i) offs[i] = so[i];
  }
  __syncthreads();
  int bt = blockIdx.x;
  int n = cnt[bt], o = so[bt];
  for (int j = threadIdx.x; j < n; j += 256) glob[o + j] = idx[bt * 2048 + j];
}

// ---------- zero-fill out rows for masked queries ----------
__global__ __launch_bounds__(256) void zerofill(const int* __restrict__ mcnt,
                                                const int* __restrict__ mlist,
                                                float* __restrict__ out) {
  int w = blockIdx.x * 4 + (threadIdx.x >> 6);
  int lane = threadIdx.x & 63;
  if (w >= *mcnt) return;
  float* row = out + (size_t)mlist[w] * 4096;
  f32x4 z = (f32x4){0.f, 0.f, 0.f, 0.f};
#pragma unroll
  for (int i = 0; i < 16; ++i) *(f32x4*)(row + i * 256 + lane * 4) = z;
}

// ---------- kv finish: sum 4 split-K partials, hi/lo split + scatter ----------
__global__ __launch_bounds__(256) void kv_finish(const float* __restrict__ kvp,
                                                 unsigned short* __restrict__ Kh,
                                                 unsigned short* __restrict__ Kl,
                                                 unsigned short* __restrict__ Vt) {
  int row = blockIdx.x;  // 0..767
  int bt = row >> 6, key = row & 63;
  int c = threadIdx.x * 4;
  const float* p = kvp + (size_t)row * 1024 + c;
  f32x4 v = *(const f32x4*)p;
#pragma unroll
  for (int sl = 1; sl < 4; ++sl)
    v += *(const f32x4*)(p + (size_t)sl * 768 * 1024);
  if (c < 512) {
    int h = c >> 6, d = c & 63;
    u16x4 hv, lv;
#pragma unroll
    for (int j = 0; j < 4; ++j) {
      unsigned short hi = f2bf(v[j]);
      hv[j] = hi;
      lv[j] = f2bf(v[j] - bf2f(hi));
    }
    size_t o = ((size_t)(bt * 8 + h) * 64 + key) * 64 + d;
    *(u16x4*)&Kh[o] = hv;
    *(u16x4*)&Kl[o] = lv;
  } else {
    int cc = c - 512;
    int h = cc >> 6, d = cc & 63;
#pragma unroll
    for (int j = 0; j < 4; ++j)
      Vt[((size_t)(bt * 8 + h) * 64 + d + j) * 64 + key] = f2bf(v[j]);
  }
}

// ---------- bf16x2 / bf16 GEMM, swizzled LDS, LDS-reshape epilogue ----------
// GA: A-tile gathered from fp32 Yf rows via glob (convert in registers,
//     swizzled ds_write_b128) — eliminates the ybf intermediate.
// EPI 1: fp32 split-K partial, compact M (bm fastest-varying)
// EPI 3: fp32 row-scatter via glob, compact M (bm fastest-varying)
// EPI 4: fp32 split-K partial, full M (kv)
#define BM 128
#define BN 128
#define BK 64

template <int EPI, int KSL, bool USE_BL, bool GA>
__global__ __launch_bounds__(256) void gemm2(
    const unsigned short* __restrict__ A, const float* __restrict__ Yf,
    const unsigned short* __restrict__ Bh, const unsigned short* __restrict__ Bl,
    void* __restrict__ Cv, const int* __restrict__ glob,
    const int* __restrict__ offs, int M, int N, int K) {
  __shared__ unsigned short smem[BM * BK + BN * BK + (USE_BL ? BN * BK : 64)];
  unsigned short* Ald = smem;
  unsigned short* Bhld = smem + BM * BK;
  unsigned short* Blld = smem + BM * BK + BN * BK;
  float* epi = (float*)smem;  // 32 KB reuse after K-loop

  int tid = threadIdx.x, lane = tid & 63, wid = tid >> 6;
  int wr = wid >> 1, wc = wid & 1;
  int nwg = gridDim.x;
  int w = (blockIdx.x & 7) * (nwg >> 3) + (blockIdx.x >> 3);  // XCD swizzle
  int nTN = N / BN;
  int bm, bn, ks;
  if constexpr (EPI == 1 || EPI == 3) {
    int nBM = M / BM;  // bm fastest: dead tiles interleave across XCDs
    bm = w % nBM;
    int r = w / nBM;
    if constexpr (KSL == 1) {
      bn = r;
      ks = 0;
    } else {
      bn = r / KSL;
      ks = r % KSL;
    }
  } else {
    if constexpr (KSL == 1) {
      bm = w / nTN;
      bn = w % nTN;
      ks = 0;
    } else {
      bm = w / (nTN * KSL);
      int r = w % (nTN * KSL);
      bn = r / KSL;
      ks = r % KSL;
    }
  }
  int mv = M;
  if constexpr (EPI == 1 || EPI == 3) mv = offs[12];
  if (bm * BM >= mv) return;

  int kbeg = ks * (K / KSL), kend = kbeg + K / KSL;
  const unsigned short* Ab = GA ? nullptr : A + (size_t)(bm * BM) * K;
  const unsigned short* Bhb = Bh + (size_t)(bn * BN) * K;
  const unsigned short* Blb = USE_BL ? Bl + (size_t)(bn * BN) * K : nullptr;
  int fr = lane & 15, fq = lane >> 4;
  int srow = lane >> 3, scol = ((lane & 7) ^ (lane >> 3)) * 8;  // pre-swizzled

  // GA: hoist gathered row pointers (k-invariant)
  const float *grow0 = nullptr, *grow1 = nullptr;
  int c8 = 0, sw0 = 0, sw1 = 0, lrow0 = 0, lrow1 = 0;
  if constexpr (GA) {
    int r0 = tid >> 2;
    int cseg = (tid & 3) * 16;  // fp32 col offset within BK
    c8 = cseg >> 3;             // 0,2,4,6
    lrow0 = r0;
    lrow1 = 64 + r0;
    int gr0 = bm * BM + lrow0, gr1 = bm * BM + lrow1;
    int g0 = glob[gr0 < mv ? gr0 : mv - 1];
    int g1 = glob[gr1 < mv ? gr1 : mv - 1];
    grow0 = Yf + (size_t)g0 * 4096 + cseg;
    grow1 = Yf + (size_t)g1 * 4096 + cseg;
    sw0 = lrow0 & 7;
    sw1 = lrow1 & 7;
  }

  f32x4 acc[4][4];
#pragma unroll
  for (int i = 0; i < 4; ++i)
#pragma unroll
    for (int j = 0; j < 4; ++j) acc[i][j] = (f32x4){0.f, 0.f, 0.f, 0.f};

  for (int k0 = kbeg; k0 < kend; k0 += BK) {
    if constexpr (GA) {
      // A: gather fp32 -> bf16, swizzled ds_write_b128 (write-side XOR
      // mirrors the read-side XOR; 8 bank-groups -> conflict-free)
#pragma unroll
      for (int half = 0; half < 2; ++half) {
        const float* src = (half ? grow1 : grow0) + k0;
        int lrow = half ? lrow1 : lrow0;
        int sw = half ? sw1 : sw0;
        f32x4 v0 = *(const f32x4*)(src);
        f32x4 v1 = *(const f32x4*)(src + 4);
        f32x4 v2 = *(const f32x4*)(src + 8);
        f32x4 v3 = *(const f32x4*)(src + 12);
        u16x8 o0, o1;
#pragma unroll
        for (int j = 0; j < 4; ++j) {
          o0[j] = f2bf(v0[j]);
          o0[4 + j] = f2bf(v1[j]);
          o1[j] = f2bf(v2[j]);
          o1[4 + j] = f2bf(v3[j]);
        }
        *(u16x8*)&Ald[lrow * BK + ((c8 ^ sw) << 3)] = o0;
        *(u16x8*)&Ald[lrow * BK + (((c8 + 1) ^ sw) << 3)] = o1;
      }
#pragma unroll
      for (int i = 0; i < 4; ++i) {
        int c = wid * 4 + i;
        size_t go = (size_t)(c * 8 + srow) * K + k0 + scol;
        gload_lds16(Bhb + go, &Bhld[c * 512]);
      }
    } else {
#pragma unroll
      for (int i = 0; i < 4; ++i) {
        int c = wid * 4 + i;
        size_t go = (size_t)(c * 8 + srow) * K + k0 + scol;
        gload_lds16(Ab + go, &Ald[c * 512]);
        gload_lds16(Bhb + go, &Bhld[c * 512]);
        if constexpr (USE_BL) gload_lds16(Blb + go, &Blld[c * 512]);
      }
    }
    __syncthreads();
#pragma unroll
    for (int kk = 0; kk < 2; ++kk) {
      int ca = (kk * 32 + fq * 8) ^ ((fr & 7) * 8);  // swizzled read col
      bf16x8 af[4], bhf[4], blf[4];
#pragma unroll
      for (int i = 0; i < 4; ++i) {
        af[i] = *(const bf16x8*)&Ald[(wr * 64 + i * 16 + fr) * BK + ca];
        bhf[i] = *(const bf16x8*)&Bhld[(wc * 64 + i * 16 + fr) * BK + ca];
        if constexpr (USE_BL)
          blf[i] = *(const bf16x8*)&Blld[(wc * 64 + i * 16 + fr) * BK + ca];
      }
#pragma unroll
      for (int mi = 0; mi < 4; ++mi)
#pragma unroll
        for (int ni = 0; ni < 4; ++ni) {
          acc[mi][ni] = __builtin_amdgcn_mfma_f32_16x16x32_bf16(
              af[mi], bhf[ni], acc[mi][ni], 0, 0, 0);
          if constexpr (USE_BL)
            acc[mi][ni] = __builtin_amdgcn_mfma_f32_16x16x32_bf16(
                af[mi], blf[ni], acc[mi][ni], 0, 0, 0);
        }
    }
    __syncthreads();
  }

  // LDS-reshape epilogue: 2 passes of 64 rows; 512B-contiguous row stores.
#pragma unroll 1
  for (int p = 0; p < 2; ++p) {
    __syncthreads();
    if (wr == p) {
#pragma unroll
      for (int mi = 0; mi < 4; ++mi)
#pragma unroll
        for (int ni = 0; ni < 4; ++ni)
#pragma unroll
          for (int r = 0; r < 4; ++r) {
            int lrow = mi * 16 + fq * 4 + r;
            int lcol = wc * 64 + ni * 16 + fr;
            int pc = lcol ^ ((lrow & 7) << 4);
            epi[lrow * 128 + pc] = acc[mi][ni][r];
          }
    }
    __syncthreads();
#pragma unroll
    for (int k = 0; k < 8; ++k) {
      int chunk = k * 256 + tid;
      int lrow = chunk >> 5;
      int c4 = (chunk & 31) * 4;
      int pc4 = c4 ^ ((lrow & 7) << 4);
      f32x4 v = *(f32x4*)&epi[lrow * 128 + pc4];
      int row = bm * BM + p * 64 + lrow;
      if constexpr (EPI == 1 || EPI == 4) {
        *(f32x4*)&((float*)Cv)[(size_t)ks * M * N + (size_t)row * N + bn * BN +
                               c4] = v;
      } else {  // EPI == 3
        if (row < mv)
          *(f32x4*)&((float*)Cv)[(size_t)glob[row] * N + bn * BN + c4] = v;
      }
    }
  }
}

// ---------- MFMA attention (compact positions, sums 4 q partials) ----------
__global__ __launch_bounds__(256) void attn5(
    const float* __restrict__ qc, const unsigned short* __restrict__ Kh,
    const unsigned short* __restrict__ Kl, const unsigned short* __restrict__ Vt,
    const int* __restrict__ cnt, const int* __restrict__ offs,
    unsigned short* __restrict__ attnc) {
  __shared__ unsigned short Pl[4][32][72];
  int tid = threadIdx.x, wid = tid >> 6, lane = tid & 63;
  int fr = lane & 15, fq = lane >> 4;
  int bt = blockIdx.x >> 6, rt = blockIdx.x & 63;
  int n = cnt[bt];
  int rbase = rt * 32;
  if (rbase >= n) return;
  int qbase = offs[bt] + rbase;

#pragma unroll 1
  for (int hp = 0; hp < 2; ++hp) {
    int h = wid * 2 + hp;
    const unsigned short* khb = Kh + ((size_t)(bt * 8 + h) * 64) * 64;
    const unsigned short* klb = Kl + ((size_t)(bt * 8 + h) * 64) * 64;
    const unsigned short* vtb = Vt + ((size_t)(bt * 8 + h) * 64) * 64;

    f32x4 sacc[2][4];
#pragma unroll
    for (int i = 0; i < 2; ++i)
#pragma unroll
      for (int j = 0; j < 4; ++j) sacc[i][j] = (f32x4){0.f, 0.f, 0.f, 0.f};

#pragma unroll
    for (int kk = 0; kk < 2; ++kk) {
      bf16x8 qh[2], ql[2];
#pragma unroll
      for (int mi = 0; mi < 2; ++mi) {
        size_t qo = (size_t)(qbase + mi * 16 + fr) * 512 + h * 64 + kk * 32 + fq * 8;
        f32x4 s0 = *(const f32x4*)(qc + qo);
        f32x4 s1 = *(const f32x4*)(qc + qo + 4);
#pragma unroll
        for (int sl = 1; sl < 4; ++sl) {
          s0 += *(const f32x4*)(qc + sl * QSTR + qo);
          s1 += *(const f32x4*)(qc + sl * QSTR + qo + 4);
        }
        float sv[8];
        *(f32x4*)&sv[0] = s0;
        *(f32x4*)&sv[4] = s1;
#pragma unroll
        for (int j = 0; j < 8; ++j) {
          unsigned short hi = f2bf(sv[j]);
          qh[mi][j] = (short)hi;
          ql[mi][j] = (short)f2bf(sv[j] - bf2f(hi));
        }
      }
#pragma unroll
      for (int ni = 0; ni < 4; ++ni) {
        size_t ko = (size_t)(ni * 16 + fr) * 64 + kk * 32 + fq * 8;
        bf16x8 kh = *(const bf16x8*)(khb + ko);
        bf16x8 kl = *(const bf16x8*)(klb + ko);
#pragma unroll
        for (int mi = 0; mi < 2; ++mi) {
          sacc[mi][ni] = __builtin_amdgcn_mfma_f32_16x16x32_bf16(
              qh[mi], kh, sacc[mi][ni], 0, 0, 0);
          sacc[mi][ni] = __builtin_amdgcn_mfma_f32_16x16x32_bf16(
              qh[mi], kl, sacc[mi][ni], 0, 0, 0);
          sacc[mi][ni] = __builtin_amdgcn_mfma_f32_16x16x32_bf16(
              ql[mi], kh, sacc[mi][ni], 0, 0, 0);
        }
      }
    }

#pragma unroll
    for (int mi = 0; mi < 2; ++mi) {
#pragma unroll
      for (int r = 0; r < 4; ++r) {
        float m = fmaxf(fmaxf(sacc[mi][0][r], sacc[mi][1][r]),
                        fmaxf(sacc[mi][2][r], sacc[mi][3][r]));
#pragma unroll
        for (int o = 1; o < 16; o <<= 1) m = fmaxf(m, __shfl_xor(m, o));
        float e0 = __expf(sacc[mi][0][r] - m);
        float e1 = __expf(sacc[mi][1][r] - m);
        float e2 = __expf(sacc[mi][2][r] - m);
        float e3 = __expf(sacc[mi][3][r] - m);
        float s = e0 + e1 + e2 + e3;
#pragma unroll
        for (int o = 1; o < 16; o <<= 1) s += __shfl_xor(s, o);
        float inv = 1.f / s;
        int row = mi * 16 + fq * 4 + r;
        Pl[wid][row][fr] = f2bf(e0 * inv);
        Pl[wid][row][16 + fr] = f2bf(e1 * inv);
        Pl[wid][row][32 + fr] = f2bf(e2 * inv);
        Pl[wid][row][48 + fr] = f2bf(e3 * inv);
      }
    }

    f32x4 oacc[2][4];
#pragma unroll
    for (int i = 0; i < 2; ++i)
#pragma unroll
      for (int j = 0; j < 4; ++j) oacc[i][j] = (f32x4){0.f, 0.f, 0.f, 0.f};
#pragma unroll
    for (int kk = 0; kk < 2; ++kk) {
      bf16x8 pa[2];
#pragma unroll
      for (int mi = 0; mi < 2; ++mi)
        pa[mi] = *(const bf16x8*)&Pl[wid][mi * 16 + fr][kk * 32 + fq * 8];
#pragma unroll
      for (int ni = 0; ni < 4; ++ni) {
        bf16x8 vb = *(const bf16x8*)(vtb + (size_t)(ni * 16 + fr) * 64 +
                                     kk * 32 + fq * 8);
#pragma unroll
        for (int mi = 0; mi < 2; ++mi)
          oacc[mi][ni] = __builtin_amdgcn_mfma_f32_16x16x32_bf16(
              pa[mi], vb, oacc[mi][ni], 0, 0, 0);
      }
    }

#pragma unroll
    for (int mi = 0; mi < 2; ++mi)
#pragma unroll
      for (int r = 0; r < 4; ++r) {
        int row = mi * 16 + fq * 4 + r;
        if (rbase + row < n) {
          unsigned short* ar = attnc + (size_t)(qbase + row) * 512 + h * 64 + fr;
          ar[0] = f2bf(oacc[mi][0][r]);
          ar[16] = f2bf(oacc[mi][1][r]);
          ar[32] = f2bf(oacc[mi][2][r]);
          ar[48] = f2bf(oacc[mi][3][r]);
        }
      }
  }
}

// ---------- launch ----------
extern "C" void kernel_launch(void* const* d_in, const int* in_sizes, int n_in,
                              void* d_out, int out_size, void* d_ws,
                              size_t ws_size, hipStream_t stream) {
  const float* latent = (const float*)d_in[0];
  const float* y = (const float*)d_in[1];
  const int* mask = (const int*)d_in[2];
  const float* W_vk = (const float*)d_in[3];
  const float* W_q = (const float*)d_in[4];
  const float* W_out = (const float*)d_in[5];
  float* out = (float*)d_out;

  char* ws = (char*)d_ws;
  size_t off = 0;
  auto alloc = [&](size_t bytes) -> void* {
    void* p = ws + off;
    off = (off + bytes + 255) & ~(size_t)255;
    return p;
  };
  unsigned short* WqT_h = (unsigned short*)alloc((size_t)512 * 4096 * 2);
  unsigned short* WqT_l = (unsigned short*)alloc((size_t)512 * 4096 * 2);
  unsigned short* WvkT_h = (unsigned short*)alloc((size_t)1024 * 2048 * 2);
  unsigned short* WvkT_l = (unsigned short*)alloc((size_t)1024 * 2048 * 2);
  unsigned short* WoT_h = (unsigned short*)alloc((size_t)4096 * 512 * 2);
  unsigned short* WoT_l = (unsigned short*)alloc((size_t)4096 * 512 * 2);
  unsigned short* latbf = (unsigned short*)alloc((size_t)768 * 2048 * 2);
  float* qc = (float*)alloc((size_t)4 * QCAP * 512 * 4);  // 4 split-K slices
  float* kvp = qc;  // kv partials alias qc (dead before q-GEMM writes qc)
  unsigned short* Khb = (unsigned short*)alloc((size_t)768 * 512 * 2);
  unsigned short* Klb = (unsigned short*)alloc((size_t)768 * 512 * 2);
  unsigned short* Vtb = (unsigned short*)alloc((size_t)768 * 512 * 2);
  unsigned short* attnc = (unsigned short*)alloc((size_t)8192 * 512 * 2);
  int* cnt = (int*)alloc(12 * 4);
  int* idx = (int*)alloc((size_t)12 * 2048 * 4);
  int* offs = (int*)alloc(13 * 4);
  int* glob = (int*)alloc(8192 * 4);
  int* mcnt = (int*)alloc(4);
  int* mlist = (int*)alloc(8192 * 4);

  hipMemsetAsync(cnt, 0, 12 * 4, stream);
  hipMemsetAsync(mcnt, 0, 4, stream);

  transpose_split3<<<6912, 256, 0, stream>>>(W_q, W_vk, W_out, latent, WqT_h,
                                             WqT_l, WvkT_h, WvkT_l, WoT_h,
                                             WoT_l, latbf);

  gather_rows<<<32, 256, 0, stream>>>(mask, cnt, idx, mcnt, mlist);
  scan_build<<<12, 256, 0, stream>>>(cnt, offs, idx, glob);
  zerofill<<<2048, 256, 0, stream>>>(mcnt, mlist, out);

  // kv = latent[768,2048] @ W_vk -> 4 fp32 partial slices
  gemm2<4, 4, true, false><<<(768 / BM) * (1024 / BN) * 4, 256, 0, stream>>>(
      latbf, nullptr, WvkT_h, WvkT_l, kvp, nullptr, nullptr, 768, 1024, 2048);
  kv_finish<<<768, 256, 0, stream>>>(kvp, Khb, Klb, Vtb);
  // q = gather(y)[compact,4096] @ W_q (single-bf16 B) -> 4 fp32 split-K slices
  gemm2<1, 4, false, true><<<(8192 / BM) * (512 / BN) * 4, 256, 0, stream>>>(
      nullptr, y, WqT_h, nullptr, qc, glob, offs, QCAP, 512, 4096);
  // MFMA attention (sums 4 q partials)
  attn5<<<12 * 64, 256, 0, stream>>>(qc, Khb, Klb, Vtb, cnt, offs, attnc);
  // out = attnc[compact,512] @ W_out (single-bf16 B) -> scatter fp32 rows
  gemm2<3, 1, false, false><<<(8192 / BM) * (4096 / BN), 256, 0, stream>>>(
      attnc, nullptr, WoT_h, nullptr, out, glob, offs, 8192, 4096, 512);
}

// Round 15
// 280.504 us; speedup vs baseline: 1.0649x; 1.0649x over previous
//
#include <hip/hip_runtime.h>
#include <hip/hip_bf16.h>

typedef __attribute__((ext_vector_type(4))) float f32x4;
typedef __attribute__((ext_vector_type(8))) short bf16x8;
typedef __attribute__((ext_vector_type(4))) unsigned short u16x4;
typedef __attribute__((ext_vector_type(8))) unsigned short u16x8;

#define QCAP 8256  // compact q buffer row capacity
#define QSTR ((size_t)QCAP * 512)

__device__ __forceinline__ unsigned short f2bf(float f) {
  unsigned int u = __builtin_bit_cast(unsigned int, f);
  unsigned int r = (u + 0x7FFFu + ((u >> 16) & 1u)) >> 16;
  return (unsigned short)r;
}
__device__ __forceinline__ float bf2f(unsigned short h) {
  unsigned int u = ((unsigned int)h) << 16;
  return __builtin_bit_cast(float, u);
}

__device__ __forceinline__ void gload_lds16(const void* g, void* l) {
  __builtin_amdgcn_global_load_lds(
      (__attribute__((address_space(1))) unsigned int*)g,
      (__attribute__((address_space(3))) unsigned int*)l, 16, 0, 0);
}

// ---------- gathered fp32 -> bf16 convert for y (compact valid rows) ----------
__global__ __launch_bounds__(256) void cvt_gather(
    const float* __restrict__ y, const int* __restrict__ glob,
    const int* __restrict__ offs, unsigned short* __restrict__ ybf) {
  int p = blockIdx.x >> 1, half = blockIdx.x & 1;
  if (p >= offs[12]) return;
  int g = glob[p];
  const float* src = y + (size_t)g * 4096 + half * 2048 + threadIdx.x * 8;
  unsigned short* dst = ybf + (size_t)p * 4096 + half * 2048 + threadIdx.x * 8;
  f32x4 a = *(const f32x4*)src;
  f32x4 b = *(const f32x4*)(src + 4);
  u16x8 o;
#pragma unroll
  for (int j = 0; j < 4; ++j) o[j] = f2bf(a[j]);
#pragma unroll
  for (int j = 0; j < 4; ++j) o[4 + j] = f2bf(b[j]);
  *(u16x8*)dst = o;
}

// ---------- fused: 3 weight transposes + latent bf16 convert (1 launch) ----------
// lo-half written only when Tl != nullptr (only W_vk needs hi/lo now)
__global__ __launch_bounds__(256) void transpose_split3(
    const float* __restrict__ Wq, const float* __restrict__ Wvk,
    const float* __restrict__ Wo, const float* __restrict__ latent,
    unsigned short* __restrict__ QTh, unsigned short* __restrict__ VKh,
    unsigned short* __restrict__ VKl, unsigned short* __restrict__ OTh,
    unsigned short* __restrict__ latbf) {
  int bid = blockIdx.x;
  if (bid >= 6144) {  // latent convert
    long i = ((long)(bid - 6144) * 256 + threadIdx.x) * 8;
    f32x4 a = *(const f32x4*)(latent + i);
    f32x4 b = *(const f32x4*)(latent + i + 4);
    u16x8 o;
#pragma unroll
    for (int j = 0; j < 4; ++j) o[j] = f2bf(a[j]);
#pragma unroll
    for (int j = 0; j < 4; ++j) o[4 + j] = f2bf(b[j]);
    *(u16x8*)(latbf + i) = o;
    return;
  }
  __shared__ float tile[32][33];
  const float* W;
  unsigned short *Th, *Tl;
  int K, N, nbx, b;
  if (bid < 2048) {
    W = Wq; Th = QTh; Tl = nullptr; K = 4096; N = 512; nbx = 16; b = bid;
  } else if (bid < 4096) {
    W = Wvk; Th = VKh; Tl = VKl; K = 2048; N = 1024; nbx = 32; b = bid - 2048;
  } else {
    W = Wo; Th = OTh; Tl = nullptr; K = 512; N = 4096; nbx = 128; b = bid - 4096;
  }
  int n0 = (b % nbx) * 32, k0 = (b / nbx) * 32;
  int tx = threadIdx.x & 31, ty = threadIdx.x >> 5;
#pragma unroll
  for (int r = 0; r < 4; ++r)
    tile[ty + 8 * r][tx] = W[(size_t)(k0 + ty + 8 * r) * N + n0 + tx];
  __syncthreads();
#pragma unroll
  for (int r = 0; r < 4; ++r) {
    float f = tile[tx][ty + 8 * r];
    unsigned short hi = f2bf(f);
    size_t o = (size_t)(n0 + ty + 8 * r) * K + k0 + tx;
    Th[o] = hi;
    if (Tl) Tl[o] = f2bf(f - bf2f(hi));
  }
}

// ---------- gather rows by (b, t); also collect masked rows ----------
__global__ __launch_bounds__(256) void gather_rows(const int* __restrict__ mask,
                                                   int* __restrict__ cnt,
                                                   int* __restrict__ idx,
                                                   int* __restrict__ mcnt,
                                                   int* __restrict__ mlist) {
  int g = blockIdx.x * 256 + threadIdx.x;
  int m = mask[g];
  if (m > 0) {
    int bt = (g >> 11) * 3 + m - 1;
    int p = atomicAdd(&cnt[bt], 1);
    idx[bt * 2048 + p] = g;
  } else {
    int p = atomicAdd(mcnt, 1);
    mlist[p] = g;
  }
}

// ---------- scan (local) + build bucket-major compact list ----------
__global__ __launch_bounds__(256) void scan_build(const int* __restrict__ cnt,
                                                  int* __restrict__ offs,
                                                  const int* __restrict__ idx,
                                                  int* __restrict__ glob) {
  __shared__ int so[13];
  if (threadIdx.x == 0) {
    int s = 0;
#pragma unroll
    for (int i = 0; i < 12; ++i) {
      so[i] = s;
      s += cnt[i];
    }
    so[12] = s;
    if (blockIdx.x == 0)
#pragma unroll
      for (int i = 0; i < 13; ++i) offs[i] = so[i];
  }
  __syncthreads();
  int bt = blockIdx.x;
  int n = cnt[bt], o = so[bt];
  for (int j = threadIdx.x; j < n; j += 256) glob[o + j] = idx[bt * 2048 + j];
}

// ---------- kv finish: sum 4 split-K partials, hi/lo split + scatter ----------
__global__ __launch_bounds__(256) void kv_finish(const float* __restrict__ kvp,
                                                 unsigned short* __restrict__ Kh,
                                                 unsigned short* __restrict__ Kl,
                                                 unsigned short* __restrict__ Vt) {
  int row = blockIdx.x;  // 0..767
  int bt = row >> 6, key = row & 63;
  int c = threadIdx.x * 4;
  const float* p = kvp + (size_t)row * 1024 + c;
  f32x4 v = *(const f32x4*)p;
#pragma unroll
  for (int sl = 1; sl < 4; ++sl)
    v += *(const f32x4*)(p + (size_t)sl * 768 * 1024);
  if (c < 512) {
    int h = c >> 6, d = c & 63;
    u16x4 hv, lv;
#pragma unroll
    for (int j = 0; j < 4; ++j) {
      unsigned short hi = f2bf(v[j]);
      hv[j] = hi;
      lv[j] = f2bf(v[j] - bf2f(hi));
    }
    size_t o = ((size_t)(bt * 8 + h) * 64 + key) * 64 + d;
    *(u16x4*)&Kh[o] = hv;
    *(u16x4*)&Kl[o] = lv;
  } else {
    int cc = c - 512;
    int h = cc >> 6, d = cc & 63;
#pragma unroll
    for (int j = 0; j < 4; ++j)
      Vt[((size_t)(bt * 8 + h) * 64 + d + j) * 64 + key] = f2bf(v[j]);
  }
}

// ---------- bf16x2 / bf16 GEMM, swizzled LDS, LDS-reshape epilogue ----------
// EPI 1: fp32 split-K partial, compact M (bm fastest-varying)
// EPI 3: fp32 row-scatter via glob, compact M; DEAD blocks zero-fill the
//        masked out-rows (fused zerofill, overlaps GEMM)
// EPI 4: fp32 split-K partial, full M (kv)
#define BM 128
#define BN 128
#define BK 64

template <int EPI, int KSL, bool USE_BL>
__global__ __launch_bounds__(256) void gemm2(
    const unsigned short* __restrict__ A, const unsigned short* __restrict__ Bh,
    const unsigned short* __restrict__ Bl, void* __restrict__ Cv,
    const int* __restrict__ glob, const int* __restrict__ offs,
    const int* __restrict__ mcnt, const int* __restrict__ mlist, int M, int N,
    int K) {
  __shared__ unsigned short smem[BM * BK + BN * BK + (USE_BL ? BN * BK : 64)];
  unsigned short* Ald = smem;
  unsigned short* Bhld = smem + BM * BK;
  unsigned short* Blld = smem + BM * BK + BN * BK;
  float* epi = (float*)smem;  // 32 KB reuse after K-loop

  int tid = threadIdx.x, lane = tid & 63, wid = tid >> 6;
  int wr = wid >> 1, wc = wid & 1;
  int nwg = gridDim.x;
  int w = (blockIdx.x & 7) * (nwg >> 3) + (blockIdx.x >> 3);  // XCD swizzle
  int nTN = N / BN;
  int bm, bn, ks;
  if constexpr (EPI == 1 || EPI == 3) {
    int nBM = M / BM;  // bm fastest: dead tiles interleave across XCDs
    bm = w % nBM;
    int r = w / nBM;
    if constexpr (KSL == 1) {
      bn = r;
      ks = 0;
    } else {
      bn = r / KSL;
      ks = r % KSL;
    }
  } else {
    if constexpr (KSL == 1) {
      bm = w / nTN;
      bn = w % nTN;
      ks = 0;
    } else {
      bm = w / (nTN * KSL);
      int r = w % (nTN * KSL);
      bn = r / KSL;
      ks = r % KSL;
    }
  }
  int mv = M;
  if constexpr (EPI == 1 || EPI == 3) mv = offs[12];

  if (bm * BM >= mv) {
    // dead block: for EPI 3, zero-fill masked output rows instead of exiting
    if constexpr (EPI == 3) {
      int nBM = M / BM;
      int bmLive = (mv + BM - 1) / BM;
      int nDead = (nBM - bmLive) * nTN;
      int deadIdx = (bm - bmLive) + bn * (nBM - bmLive);
      int nm = *mcnt;
      f32x4 z = (f32x4){0.f, 0.f, 0.f, 0.f};
      for (int j = deadIdx; j < nm; j += nDead) {
        float* row = (float*)Cv + (size_t)mlist[j] * N;
#pragma unroll
        for (int i = 0; i < 4; ++i)
          *(f32x4*)&row[(i * 256 + tid) * 4] = z;
      }
    }
    return;
  }

  int kbeg = ks * (K / KSL), kend = kbeg + K / KSL;
  const unsigned short* Ab = A + (size_t)(bm * BM) * K;
  const unsigned short* Bhb = Bh + (size_t)(bn * BN) * K;
  const unsigned short* Blb = USE_BL ? Bl + (size_t)(bn * BN) * K : nullptr;
  int fr = lane & 15, fq = lane >> 4;
  int srow = lane >> 3, scol = ((lane & 7) ^ (lane >> 3)) * 8;  // pre-swizzled

  f32x4 acc[4][4];
#pragma unroll
  for (int i = 0; i < 4; ++i)
#pragma unroll
    for (int j = 0; j < 4; ++j) acc[i][j] = (f32x4){0.f, 0.f, 0.f, 0.f};

  for (int k0 = kbeg; k0 < kend; k0 += BK) {
#pragma unroll
    for (int i = 0; i < 4; ++i) {
      int c = wid * 4 + i;
      size_t go = (size_t)(c * 8 + srow) * K + k0 + scol;
      gload_lds16(Ab + go, &Ald[c * 512]);
      gload_lds16(Bhb + go, &Bhld[c * 512]);
      if constexpr (USE_BL) gload_lds16(Blb + go, &Blld[c * 512]);
    }
    __syncthreads();
#pragma unroll
    for (int kk = 0; kk < 2; ++kk) {
      int ca = (kk * 32 + fq * 8) ^ ((fr & 7) * 8);  // swizzled read col
      bf16x8 af[4], bhf[4], blf[4];
#pragma unroll
      for (int i = 0; i < 4; ++i) {
        af[i] = *(const bf16x8*)&Ald[(wr * 64 + i * 16 + fr) * BK + ca];
        bhf[i] = *(const bf16x8*)&Bhld[(wc * 64 + i * 16 + fr) * BK + ca];
        if constexpr (USE_BL)
          blf[i] = *(const bf16x8*)&Blld[(wc * 64 + i * 16 + fr) * BK + ca];
      }
#pragma unroll
      for (int mi = 0; mi < 4; ++mi)
#pragma unroll
        for (int ni = 0; ni < 4; ++ni) {
          acc[mi][ni] = __builtin_amdgcn_mfma_f32_16x16x32_bf16(
              af[mi], bhf[ni], acc[mi][ni], 0, 0, 0);
          if constexpr (USE_BL)
            acc[mi][ni] = __builtin_amdgcn_mfma_f32_16x16x32_bf16(
                af[mi], blf[ni], acc[mi][ni], 0, 0, 0);
        }
    }
    __syncthreads();
  }

  // LDS-reshape epilogue: 2 passes of 64 rows; 512B-contiguous row stores.
#pragma unroll 1
  for (int p = 0; p < 2; ++p) {
    __syncthreads();
    if (wr == p) {
#pragma unroll
      for (int mi = 0; mi < 4; ++mi)
#pragma unroll
        for (int ni = 0; ni < 4; ++ni)
#pragma unroll
          for (int r = 0; r < 4; ++r) {
            int lrow = mi * 16 + fq * 4 + r;
            int lcol = wc * 64 + ni * 16 + fr;
            int pc = lcol ^ ((lrow & 7) << 4);
            epi[lrow * 128 + pc] = acc[mi][ni][r];
          }
    }
    __syncthreads();
#pragma unroll
    for (int k = 0; k < 8; ++k) {
      int chunk = k * 256 + tid;
      int lrow = chunk >> 5;
      int c4 = (chunk & 31) * 4;
      int pc4 = c4 ^ ((lrow & 7) << 4);
      f32x4 v = *(f32x4*)&epi[lrow * 128 + pc4];
      int row = bm * BM + p * 64 + lrow;
      if constexpr (EPI == 1 || EPI == 4) {
        *(f32x4*)&((float*)Cv)[(size_t)ks * M * N + (size_t)row * N + bn * BN +
                               c4] = v;
      } else {  // EPI == 3
        if (row < mv)
          *(f32x4*)&((float*)Cv)[(size_t)glob[row] * N + bn * BN + c4] = v;
      }
    }
  }

  // rare fallback: masked rows exist but no dead blocks (mv > M - BM)
  if constexpr (EPI == 3) {
    int nBM = M / BM;
    int bmLive = (mv + BM - 1) / BM;
    if (bmLive == nBM && bm == 0) {
      int nm = *mcnt;
      f32x4 z = (f32x4){0.f, 0.f, 0.f, 0.f};
      for (int j = bn; j < nm; j += nTN) {
        float* row = (float*)Cv + (size_t)mlist[j] * N;
#pragma unroll
        for (int i = 0; i < 4; ++i)
          *(f32x4*)&row[(i * 256 + tid) * 4] = z;
      }
    }
  }
}

// ---------- MFMA attention (compact positions, sums 4 q partials) ----------
__global__ __launch_bounds__(256) void attn5(
    const float* __restrict__ qc, const unsigned short* __restrict__ Kh,
    const unsigned short* __restrict__ Kl, const unsigned short* __restrict__ Vt,
    const int* __restrict__ cnt, const int* __restrict__ offs,
    unsigned short* __restrict__ attnc) {
  __shared__ unsigned short Pl[4][32][72];
  int tid = threadIdx.x, wid = tid >> 6, lane = tid & 63;
  int fr = lane & 15, fq = lane >> 4;
  int bt = blockIdx.x >> 6, rt = blockIdx.x & 63;
  int n = cnt[bt];
  int rbase = rt * 32;
  if (rbase >= n) return;
  int qbase = offs[bt] + rbase;

#pragma unroll 1
  for (int hp = 0; hp < 2; ++hp) {
    int h = wid * 2 + hp;
    const unsigned short* khb = Kh + ((size_t)(bt * 8 + h) * 64) * 64;
    const unsigned short* klb = Kl + ((size_t)(bt * 8 + h) * 64) * 64;
    const unsigned short* vtb = Vt + ((size_t)(bt * 8 + h) * 64) * 64;

    f32x4 sacc[2][4];
#pragma unroll
    for (int i = 0; i < 2; ++i)
#pragma unroll
      for (int j = 0; j < 4; ++j) sacc[i][j] = (f32x4){0.f, 0.f, 0.f, 0.f};

#pragma unroll
    for (int kk = 0; kk < 2; ++kk) {
      bf16x8 qh[2], ql[2];
#pragma unroll
      for (int mi = 0; mi < 2; ++mi) {
        size_t qo = (size_t)(qbase + mi * 16 + fr) * 512 + h * 64 + kk * 32 + fq * 8;
        f32x4 s0 = *(const f32x4*)(qc + qo);
        f32x4 s1 = *(const f32x4*)(qc + qo + 4);
#pragma unroll
        for (int sl = 1; sl < 4; ++sl) {
          s0 += *(const f32x4*)(qc + sl * QSTR + qo);
          s1 += *(const f32x4*)(qc + sl * QSTR + qo + 4);
        }
        float sv[8];
        *(f32x4*)&sv[0] = s0;
        *(f32x4*)&sv[4] = s1;
#pragma unroll
        for (int j = 0; j < 8; ++j) {
          unsigned short hi = f2bf(sv[j]);
          qh[mi][j] = (short)hi;
          ql[mi][j] = (short)f2bf(sv[j] - bf2f(hi));
        }
      }
#pragma unroll
      for (int ni = 0; ni < 4; ++ni) {
        size_t ko = (size_t)(ni * 16 + fr) * 64 + kk * 32 + fq * 8;
        bf16x8 kh = *(const bf16x8*)(khb + ko);
        bf16x8 kl = *(const bf16x8*)(klb + ko);
#pragma unroll
        for (int mi = 0; mi < 2; ++mi) {
          sacc[mi][ni] = __builtin_amdgcn_mfma_f32_16x16x32_bf16(
              qh[mi], kh, sacc[mi][ni], 0, 0, 0);
          sacc[mi][ni] = __builtin_amdgcn_mfma_f32_16x16x32_bf16(
              qh[mi], kl, sacc[mi][ni], 0, 0, 0);
          sacc[mi][ni] = __builtin_amdgcn_mfma_f32_16x16x32_bf16(
              ql[mi], kh, sacc[mi][ni], 0, 0, 0);
        }
      }
    }

#pragma unroll
    for (int mi = 0; mi < 2; ++mi) {
#pragma unroll
      for (int r = 0; r < 4; ++r) {
        float m = fmaxf(fmaxf(sacc[mi][0][r], sacc[mi][1][r]),
                        fmaxf(sacc[mi][2][r], sacc[mi][3][r]));
#pragma unroll
        for (int o = 1; o < 16; o <<= 1) m = fmaxf(m, __shfl_xor(m, o));
        float e0 = __expf(sacc[mi][0][r] - m);
        float e1 = __expf(sacc[mi][1][r] - m);
        float e2 = __expf(sacc[mi][2][r] - m);
        float e3 = __expf(sacc[mi][3][r] - m);
        float s = e0 + e1 + e2 + e3;
#pragma unroll
        for (int o = 1; o < 16; o <<= 1) s += __shfl_xor(s, o);
        float inv = 1.f / s;
        int row = mi * 16 + fq * 4 + r;
        Pl[wid][row][fr] = f2bf(e0 * inv);
        Pl[wid][row][16 + fr] = f2bf(e1 * inv);
        Pl[wid][row][32 + fr] = f2bf(e2 * inv);
        Pl[wid][row][48 + fr] = f2bf(e3 * inv);
      }
    }

    f32x4 oacc[2][4];
#pragma unroll
    for (int i = 0; i < 2; ++i)
#pragma unroll
      for (int j = 0; j < 4; ++j) oacc[i][j] = (f32x4){0.f, 0.f, 0.f, 0.f};
#pragma unroll
    for (int kk = 0; kk < 2; ++kk) {
      bf16x8 pa[2];
#pragma unroll
      for (int mi = 0; mi < 2; ++mi)
        pa[mi] = *(const bf16x8*)&Pl[wid][mi * 16 + fr][kk * 32 + fq * 8];
#pragma unroll
      for (int ni = 0; ni < 4; ++ni) {
        bf16x8 vb = *(const bf16x8*)(vtb + (size_t)(ni * 16 + fr) * 64 +
                                     kk * 32 + fq * 8);
#pragma unroll
        for (int mi = 0; mi < 2; ++mi)
          oacc[mi][ni] = __builtin_amdgcn_mfma_f32_16x16x32_bf16(
              pa[mi], vb, oacc[mi][ni], 0, 0, 0);
      }
    }

#pragma unroll
    for (int mi = 0; mi < 2; ++mi)
#pragma unroll
      for (int r = 0; r < 4; ++r) {
        int row = mi * 16 + fq * 4 + r;
        if (rbase + row < n) {
          unsigned short* ar = attnc + (size_t)(qbase + row) * 512 + h * 64 + fr;
          ar[0] = f2bf(oacc[mi][0][r]);
          ar[16] = f2bf(oacc[mi][1][r]);
          ar[32] = f2bf(oacc[mi][2][r]);
          ar[48] = f2bf(oacc[mi][3][r]);
        }
      }
  }
}

// ---------- launch ----------
extern "C" void kernel_launch(void* const* d_in, const int* in_sizes, int n_in,
                              void* d_out, int out_size, void* d_ws,
                              size_t ws_size, hipStream_t stream) {
  const float* latent = (const float*)d_in[0];
  const float* y = (const float*)d_in[1];
  const int* mask = (const int*)d_in[2];
  const float* W_vk = (const float*)d_in[3];
  const float* W_q = (const float*)d_in[4];
  const float* W_out = (const float*)d_in[5];
  float* out = (float*)d_out;

  char* ws = (char*)d_ws;
  size_t off = 0;
  auto alloc = [&](size_t bytes) -> void* {
    void* p = ws + off;
    off = (off + bytes + 255) & ~(size_t)255;
    return p;
  };
  unsigned short* WqT_h = (unsigned short*)alloc((size_t)512 * 4096 * 2);
  unsigned short* WvkT_h = (unsigned short*)alloc((size_t)1024 * 2048 * 2);
  unsigned short* WvkT_l = (unsigned short*)alloc((size_t)1024 * 2048 * 2);
  unsigned short* WoT_h = (unsigned short*)alloc((size_t)4096 * 512 * 2);
  unsigned short* ybf = (unsigned short*)alloc((size_t)8192 * 4096 * 2);
  unsigned short* latbf = (unsigned short*)alloc((size_t)768 * 2048 * 2);
  float* qc = (float*)alloc((size_t)4 * QCAP * 512 * 4);  // 4 split-K slices
  float* kvp = qc;  // kv partials alias qc (dead before q-GEMM writes qc)
  unsigned short* Khb = (unsigned short*)alloc((size_t)768 * 512 * 2);
  unsigned short* Klb = (unsigned short*)alloc((size_t)768 * 512 * 2);
  unsigned short* Vtb = (unsigned short*)alloc((size_t)768 * 512 * 2);
  unsigned short* attnc = (unsigned short*)alloc((size_t)8192 * 512 * 2);
  int* cnt = (int*)alloc(12 * 4);
  int* idx = (int*)alloc((size_t)12 * 2048 * 4);
  int* offs = (int*)alloc(13 * 4);
  int* glob = (int*)alloc(8192 * 4);
  int* mcnt = (int*)alloc(4);
  int* mlist = (int*)alloc(8192 * 4);

  hipMemsetAsync(cnt, 0, 12 * 4, stream);
  hipMemsetAsync(mcnt, 0, 4, stream);

  transpose_split3<<<6912, 256, 0, stream>>>(W_q, W_vk, W_out, latent, WqT_h,
                                             WvkT_h, WvkT_l, WoT_h, latbf);

  gather_rows<<<32, 256, 0, stream>>>(mask, cnt, idx, mcnt, mlist);
  scan_build<<<12, 256, 0, stream>>>(cnt, offs, idx, glob);

  cvt_gather<<<16384, 256, 0, stream>>>(y, glob, offs, ybf);

  // kv = latent[768,2048] @ W_vk -> 4 fp32 partial slices
  gemm2<4, 4, true><<<(768 / BM) * (1024 / BN) * 4, 256, 0, stream>>>(
      latbf, WvkT_h, WvkT_l, kvp, nullptr, nullptr, nullptr, nullptr, 768,
      1024, 2048);
  kv_finish<<<768, 256, 0, stream>>>(kvp, Khb, Klb, Vtb);
  // q = ybf[compact,4096] @ W_q (single-bf16 B) -> 4 fp32 split-K slices
  gemm2<1, 4, false><<<(8192 / BM) * (512 / BN) * 4, 256, 0, stream>>>(
      ybf, WqT_h, nullptr, qc, nullptr, offs, nullptr, nullptr, QCAP, 512,
      4096);
  // MFMA attention (sums 4 q partials)
  attn5<<<12 * 64, 256, 0, stream>>>(qc, Khb, Klb, Vtb, cnt, offs, attnc);
  // out = attnc[compact,512] @ W_out (single-bf16 B) -> scatter fp32 rows;
  // dead blocks zero-fill masked rows (fused zerofill)
  gemm2<3, 1, false><<<(8192 / BM) * (4096 / BN), 256, 0, stream>>>(
      attnc, WoT_h, nullptr, out, glob, offs, mcnt, mlist, 8192, 4096, 512);
}

// Round 16
// 278.081 us; speedup vs baseline: 1.0741x; 1.0087x over previous
//
#include <hip/hip_runtime.h>
#include <hip/hip_bf16.h>

typedef __attribute__((ext_vector_type(4))) float f32x4;
typedef __attribute__((ext_vector_type(8))) short bf16x8;
typedef __attribute__((ext_vector_type(4))) unsigned short u16x4;
typedef __attribute__((ext_vector_type(8))) unsigned short u16x8;

#define QCAP 8256  // compact q buffer row capacity
#define QSTR ((size_t)QCAP * 512)
#define KVB 384    // kv blocks in gemm_dual: 6 bm x 8 bn x 4 ks x 2 part

__device__ __forceinline__ unsigned short f2bf(float f) {
  unsigned int u = __builtin_bit_cast(unsigned int, f);
  unsigned int r = (u + 0x7FFFu + ((u >> 16) & 1u)) >> 16;
  return (unsigned short)r;
}
__device__ __forceinline__ float bf2f(unsigned short h) {
  unsigned int u = ((unsigned int)h) << 16;
  return __builtin_bit_cast(float, u);
}

__device__ __forceinline__ void gload_lds16(const void* g, void* l) {
  __builtin_amdgcn_global_load_lds(
      (__attribute__((address_space(1))) unsigned int*)g,
      (__attribute__((address_space(3))) unsigned int*)l, 16, 0, 0);
}

// ---------- gathered fp32 -> bf16 convert for y (compact valid rows) ----------
__global__ __launch_bounds__(256) void cvt_gather(
    const float* __restrict__ y, const int* __restrict__ glob,
    const int* __restrict__ offs, unsigned short* __restrict__ ybf) {
  int p = blockIdx.x >> 1, half = blockIdx.x & 1;
  if (p >= offs[12]) return;
  int g = glob[p];
  const float* src = y + (size_t)g * 4096 + half * 2048 + threadIdx.x * 8;
  unsigned short* dst = ybf + (size_t)p * 4096 + half * 2048 + threadIdx.x * 8;
  f32x4 a = *(const f32x4*)src;
  f32x4 b = *(const f32x4*)(src + 4);
  u16x8 o;
#pragma unroll
  for (int j = 0; j < 4; ++j) o[j] = f2bf(a[j]);
#pragma unroll
  for (int j = 0; j < 4; ++j) o[4 + j] = f2bf(b[j]);
  *(u16x8*)dst = o;
}

// ---------- fused: weight transposes + latent convert + mask gather ----------
// bid [0,2048): W_q; [2048,4096): W_vk (hi+lo); [4096,6144): W_out;
// [6144,6912): latent convert; [6912,6944): gather_rows
__global__ __launch_bounds__(256) void prep_fused(
    const float* __restrict__ Wq, const float* __restrict__ Wvk,
    const float* __restrict__ Wo, const float* __restrict__ latent,
    const int* __restrict__ mask, unsigned short* __restrict__ QTh,
    unsigned short* __restrict__ VKh, unsigned short* __restrict__ VKl,
    unsigned short* __restrict__ OTh, unsigned short* __restrict__ latbf,
    int* __restrict__ cnt, int* __restrict__ idx, int* __restrict__ mcnt,
    int* __restrict__ mlist) {
  int bid = blockIdx.x;
  if (bid >= 6912) {  // gather rows by (b,t)
    int g = (bid - 6912) * 256 + threadIdx.x;
    int m = mask[g];
    if (m > 0) {
      int bt = (g >> 11) * 3 + m - 1;
      int p = atomicAdd(&cnt[bt], 1);
      idx[bt * 2048 + p] = g;
    } else {
      int p = atomicAdd(mcnt, 1);
      mlist[p] = g;
    }
    return;
  }
  if (bid >= 6144) {  // latent convert
    long i = ((long)(bid - 6144) * 256 + threadIdx.x) * 8;
    f32x4 a = *(const f32x4*)(latent + i);
    f32x4 b = *(const f32x4*)(latent + i + 4);
    u16x8 o;
#pragma unroll
    for (int j = 0; j < 4; ++j) o[j] = f2bf(a[j]);
#pragma unroll
    for (int j = 0; j < 4; ++j) o[4 + j] = f2bf(b[j]);
    *(u16x8*)(latbf + i) = o;
    return;
  }
  __shared__ float tile[32][33];
  const float* W;
  unsigned short *Th, *Tl;
  int K, N, nbx, b;
  if (bid < 2048) {
    W = Wq; Th = QTh; Tl = nullptr; K = 4096; N = 512; nbx = 16; b = bid;
  } else if (bid < 4096) {
    W = Wvk; Th = VKh; Tl = VKl; K = 2048; N = 1024; nbx = 32; b = bid - 2048;
  } else {
    W = Wo; Th = OTh; Tl = nullptr; K = 512; N = 4096; nbx = 128; b = bid - 4096;
  }
  int n0 = (b % nbx) * 32, k0 = (b / nbx) * 32;
  int tx = threadIdx.x & 31, ty = threadIdx.x >> 5;
#pragma unroll
  for (int r = 0; r < 4; ++r)
    tile[ty + 8 * r][tx] = W[(size_t)(k0 + ty + 8 * r) * N + n0 + tx];
  __syncthreads();
#pragma unroll
  for (int r = 0; r < 4; ++r) {
    float f = tile[tx][ty + 8 * r];
    unsigned short hi = f2bf(f);
    size_t o = (size_t)(n0 + ty + 8 * r) * K + k0 + tx;
    Th[o] = hi;
    if (Tl) Tl[o] = f2bf(f - bf2f(hi));
  }
}

// ---------- scan (local) + build bucket-major compact list ----------
__global__ __launch_bounds__(256) void scan_build(const int* __restrict__ cnt,
                                                  int* __restrict__ offs,
                                                  const int* __restrict__ idx,
                                                  int* __restrict__ glob) {
  __shared__ int so[13];
  if (threadIdx.x == 0) {
    int s = 0;
#pragma unroll
    for (int i = 0; i < 12; ++i) {
      so[i] = s;
      s += cnt[i];
    }
    so[12] = s;
    if (blockIdx.x == 0)
#pragma unroll
      for (int i = 0; i < 13; ++i) offs[i] = so[i];
  }
  __syncthreads();
  int bt = blockIdx.x;
  int n = cnt[bt], o = so[bt];
  for (int j = threadIdx.x; j < n; j += 256) glob[o + j] = idx[bt * 2048 + j];
}

// ---------- kv finish: sum 8 partial slices (4 ks x 2 hi/lo parts) ----------
__global__ __launch_bounds__(256) void kv_finish(const float* __restrict__ kvp,
                                                 unsigned short* __restrict__ Kh,
                                                 unsigned short* __restrict__ Kl,
                                                 unsigned short* __restrict__ Vt) {
  int row = blockIdx.x;  // 0..767
  int bt = row >> 6, key = row & 63;
  int c = threadIdx.x * 4;
  const float* p = kvp + (size_t)row * 1024 + c;
  f32x4 v = *(const f32x4*)p;
#pragma unroll
  for (int sl = 1; sl < 8; ++sl)
    v += *(const f32x4*)(p + (size_t)sl * 768 * 1024);
  if (c < 512) {
    int h = c >> 6, d = c & 63;
    u16x4 hv, lv;
#pragma unroll
    for (int j = 0; j < 4; ++j) {
      unsigned short hi = f2bf(v[j]);
      hv[j] = hi;
      lv[j] = f2bf(v[j] - bf2f(hi));
    }
    size_t o = ((size_t)(bt * 8 + h) * 64 + key) * 64 + d;
    *(u16x4*)&Kh[o] = hv;
    *(u16x4*)&Kl[o] = lv;
  } else {
    int cc = c - 512;
    int h = cc >> 6, d = cc & 63;
#pragma unroll
    for (int j = 0; j < 4; ++j)
      Vt[((size_t)(bt * 8 + h) * 64 + d + j) * 64 + key] = f2bf(v[j]);
  }
}

#define BM 128
#define BN 128
#define BK 64

// ---------- combined kv + q GEMM (single dispatch, single-B, 32.9KB LDS) ----
// blocks [0,KVB): kv partials — slice = part*4+ks, B = (part? VKl : VKh)
// blocks [KVB,KVB+1024): q partials, compact M (bm fastest-varying)
__global__ __launch_bounds__(256) void gemm_dual(
    const unsigned short* __restrict__ latbf, const unsigned short* __restrict__ VKh,
    const unsigned short* __restrict__ VKl, const unsigned short* __restrict__ ybf,
    const unsigned short* __restrict__ QTh, float* __restrict__ kvp,
    float* __restrict__ qc, const int* __restrict__ offs) {
  __shared__ unsigned short smem[BM * BK + BN * BK + 64];
  unsigned short* Ald = smem;
  unsigned short* Bhld = smem + BM * BK;
  float* epi = (float*)smem;

  int tid = threadIdx.x, lane = tid & 63, wid = tid >> 6;
  int wr = wid >> 1, wc = wid & 1;
  const unsigned short *Ab, *Bb;
  float* Cv;
  int N, K, kbeg, kend, bm, bn;
  size_t outOff;
  if (blockIdx.x < KVB) {
    int w = (blockIdx.x & 7) * (KVB >> 3) + (blockIdx.x >> 3);  // XCD swizzle
    bm = w / 64;
    int r = w % 64;
    bn = r >> 3;
    int slice = r & 7, ks = slice & 3;
    Ab = latbf + (size_t)(bm * BM) * 2048;
    Bb = (slice < 4 ? VKh : VKl) + (size_t)(bn * BN) * 2048;
    Cv = kvp;
    N = 1024;
    K = 2048;
    kbeg = ks * 512;
    kend = kbeg + 512;
    outOff = (size_t)slice * 768 * 1024;
  } else {
    int qb = blockIdx.x - KVB;
    int w = (qb & 7) * 128 + (qb >> 3);  // XCD swizzle over 1024
    bm = w & 63;                         // bm fastest: dead tiles interleave
    int r = w >> 6;
    bn = r >> 2;
    int ks = r & 3;
    if (bm * BM >= offs[12]) return;  // compacted-away tile
    Ab = ybf + (size_t)(bm * BM) * 4096;
    Bb = QTh + (size_t)(bn * BN) * 4096;
    Cv = qc;
    N = 512;
    K = 4096;
    kbeg = ks * 1024;
    kend = kbeg + 1024;
    outOff = (size_t)ks * QSTR;
  }

  int fr = lane & 15, fq = lane >> 4;
  int srow = lane >> 3, scol = ((lane & 7) ^ (lane >> 3)) * 8;  // pre-swizzled

  f32x4 acc[4][4];
#pragma unroll
  for (int i = 0; i < 4; ++i)
#pragma unroll
    for (int j = 0; j < 4; ++j) acc[i][j] = (f32x4){0.f, 0.f, 0.f, 0.f};

  for (int k0 = kbeg; k0 < kend; k0 += BK) {
#pragma unroll
    for (int i = 0; i < 4; ++i) {
      int c = wid * 4 + i;
      size_t go = (size_t)(c * 8 + srow) * K + k0 + scol;
      gload_lds16(Ab + go, &Ald[c * 512]);
      gload_lds16(Bb + go, &Bhld[c * 512]);
    }
    __syncthreads();
#pragma unroll
    for (int kk = 0; kk < 2; ++kk) {
      int ca = (kk * 32 + fq * 8) ^ ((fr & 7) * 8);  // swizzled read col
      bf16x8 af[4], bf[4];
#pragma unroll
      for (int i = 0; i < 4; ++i) {
        af[i] = *(const bf16x8*)&Ald[(wr * 64 + i * 16 + fr) * BK + ca];
        bf[i] = *(const bf16x8*)&Bhld[(wc * 64 + i * 16 + fr) * BK + ca];
      }
#pragma unroll
      for (int mi = 0; mi < 4; ++mi)
#pragma unroll
        for (int ni = 0; ni < 4; ++ni)
          acc[mi][ni] = __builtin_amdgcn_mfma_f32_16x16x32_bf16(
              af[mi], bf[ni], acc[mi][ni], 0, 0, 0);
    }
    __syncthreads();
  }

  // LDS-reshape epilogue: 512B-contiguous stores
#pragma unroll 1
  for (int p = 0; p < 2; ++p) {
    __syncthreads();
    if (wr == p) {
#pragma unroll
      for (int mi = 0; mi < 4; ++mi)
#pragma unroll
        for (int ni = 0; ni < 4; ++ni)
#pragma unroll
          for (int r = 0; r < 4; ++r) {
            int lrow = mi * 16 + fq * 4 + r;
            int lcol = wc * 64 + ni * 16 + fr;
            int pc = lcol ^ ((lrow & 7) << 4);
            epi[lrow * 128 + pc] = acc[mi][ni][r];
          }
    }
    __syncthreads();
#pragma unroll
    for (int k = 0; k < 8; ++k) {
      int chunk = k * 256 + tid;
      int lrow = chunk >> 5;
      int c4 = (chunk & 31) * 4;
      int pc4 = c4 ^ ((lrow & 7) << 4);
      f32x4 v = *(f32x4*)&epi[lrow * 128 + pc4];
      int row = bm * BM + p * 64 + lrow;
      *(f32x4*)&Cv[outOff + (size_t)row * N + bn * BN + c4] = v;
    }
  }
}

// ---------- out-GEMM: bf16 single-B, row-scatter, fused zerofill ----------
__global__ __launch_bounds__(256) void gemm_out(
    const unsigned short* __restrict__ A, const unsigned short* __restrict__ Bh,
    float* __restrict__ Cv, const int* __restrict__ glob,
    const int* __restrict__ offs, const int* __restrict__ mcnt,
    const int* __restrict__ mlist, int M, int N, int K) {
  __shared__ unsigned short smem[BM * BK + BN * BK + 64];
  unsigned short* Ald = smem;
  unsigned short* Bhld = smem + BM * BK;
  float* epi = (float*)smem;

  int tid = threadIdx.x, lane = tid & 63, wid = tid >> 6;
  int wr = wid >> 1, wc = wid & 1;
  int nwg = gridDim.x;
  int w = (blockIdx.x & 7) * (nwg >> 3) + (blockIdx.x >> 3);
  int nTN = N / BN;
  int nBM = M / BM;
  int bm = w % nBM;
  int bn = w / nBM;
  int mv = offs[12];

  if (bm * BM >= mv) {
    // dead block: zero-fill masked output rows
    int bmLive = (mv + BM - 1) / BM;
    int nDead = (nBM - bmLive) * nTN;
    int deadIdx = (bm - bmLive) + bn * (nBM - bmLive);
    int nm = *mcnt;
    f32x4 z = (f32x4){0.f, 0.f, 0.f, 0.f};
    for (int j = deadIdx; j < nm; j += nDead) {
      float* row = Cv + (size_t)mlist[j] * N;
#pragma unroll
      for (int i = 0; i < 4; ++i) *(f32x4*)&row[(i * 256 + tid) * 4] = z;
    }
    return;
  }

  const unsigned short* Ab = A + (size_t)(bm * BM) * K;
  const unsigned short* Bhb = Bh + (size_t)(bn * BN) * K;
  int fr = lane & 15, fq = lane >> 4;
  int srow = lane >> 3, scol = ((lane & 7) ^ (lane >> 3)) * 8;

  f32x4 acc[4][4];
#pragma unroll
  for (int i = 0; i < 4; ++i)
#pragma unroll
    for (int j = 0; j < 4; ++j) acc[i][j] = (f32x4){0.f, 0.f, 0.f, 0.f};

  for (int k0 = 0; k0 < K; k0 += BK) {
#pragma unroll
    for (int i = 0; i < 4; ++i) {
      int c = wid * 4 + i;
      size_t go = (size_t)(c * 8 + srow) * K + k0 + scol;
      gload_lds16(Ab + go, &Ald[c * 512]);
      gload_lds16(Bhb + go, &Bhld[c * 512]);
    }
    __syncthreads();
#pragma unroll
    for (int kk = 0; kk < 2; ++kk) {
      int ca = (kk * 32 + fq * 8) ^ ((fr & 7) * 8);
      bf16x8 af[4], bf[4];
#pragma unroll
      for (int i = 0; i < 4; ++i) {
        af[i] = *(const bf16x8*)&Ald[(wr * 64 + i * 16 + fr) * BK + ca];
        bf[i] = *(const bf16x8*)&Bhld[(wc * 64 + i * 16 + fr) * BK + ca];
      }
#pragma unroll
      for (int mi = 0; mi < 4; ++mi)
#pragma unroll
        for (int ni = 0; ni < 4; ++ni)
          acc[mi][ni] = __builtin_amdgcn_mfma_f32_16x16x32_bf16(
              af[mi], bf[ni], acc[mi][ni], 0, 0, 0);
    }
    __syncthreads();
  }

#pragma unroll 1
  for (int p = 0; p < 2; ++p) {
    __syncthreads();
    if (wr == p) {
#pragma unroll
      for (int mi = 0; mi < 4; ++mi)
#pragma unroll
        for (int ni = 0; ni < 4; ++ni)
#pragma unroll
          for (int r = 0; r < 4; ++r) {
            int lrow = mi * 16 + fq * 4 + r;
            int lcol = wc * 64 + ni * 16 + fr;
            int pc = lcol ^ ((lrow & 7) << 4);
            epi[lrow * 128 + pc] = acc[mi][ni][r];
          }
    }
    __syncthreads();
#pragma unroll
    for (int k = 0; k < 8; ++k) {
      int chunk = k * 256 + tid;
      int lrow = chunk >> 5;
      int c4 = (chunk & 31) * 4;
      int pc4 = c4 ^ ((lrow & 7) << 4);
      f32x4 v = *(f32x4*)&epi[lrow * 128 + pc4];
      int row = bm * BM + p * 64 + lrow;
      if (row < mv)
        *(f32x4*)&Cv[(size_t)glob[row] * N + bn * BN + c4] = v;
    }
  }

  // rare fallback: masked rows exist but no dead blocks
  int bmLive = (mv + BM - 1) / BM;
  if (bmLive == nBM && bm == 0) {
    int nm = *mcnt;
    f32x4 z = (f32x4){0.f, 0.f, 0.f, 0.f};
    for (int j = bn; j < nm; j += nTN) {
      float* row = Cv + (size_t)mlist[j] * N;
#pragma unroll
      for (int i = 0; i < 4; ++i) *(f32x4*)&row[(i * 256 + tid) * 4] = z;
    }
  }
}

// ---------- MFMA attention (compact positions, sums 4 q partials) ----------
__global__ __launch_bounds__(256) void attn5(
    const float* __restrict__ qc, const unsigned short* __restrict__ Kh,
    const unsigned short* __restrict__ Kl, const unsigned short* __restrict__ Vt,
    const int* __restrict__ cnt, const int* __restrict__ offs,
    unsigned short* __restrict__ attnc) {
  __shared__ unsigned short Pl[4][32][72];
  int tid = threadIdx.x, wid = tid >> 6, lane = tid & 63;
  int fr = lane & 15, fq = lane >> 4;
  int bt = blockIdx.x >> 6, rt = blockIdx.x & 63;
  int n = cnt[bt];
  int rbase = rt * 32;
  if (rbase >= n) return;
  int qbase = offs[bt] + rbase;

#pragma unroll 1
  for (int hp = 0; hp < 2; ++hp) {
    int h = wid * 2 + hp;
    const unsigned short* khb = Kh + ((size_t)(bt * 8 + h) * 64) * 64;
    const unsigned short* klb = Kl + ((size_t)(bt * 8 + h) * 64) * 64;
    const unsigned short* vtb = Vt + ((size_t)(bt * 8 + h) * 64) * 64;

    f32x4 sacc[2][4];
#pragma unroll
    for (int i = 0; i < 2; ++i)
#pragma unroll
      for (int j = 0; j < 4; ++j) sacc[i][j] = (f32x4){0.f, 0.f, 0.f, 0.f};

#pragma unroll
    for (int kk = 0; kk < 2; ++kk) {
      bf16x8 qh[2], ql[2];
#pragma unroll
      for (int mi = 0; mi < 2; ++mi) {
        size_t qo = (size_t)(qbase + mi * 16 + fr) * 512 + h * 64 + kk * 32 + fq * 8;
        f32x4 s0 = *(const f32x4*)(qc + qo);
        f32x4 s1 = *(const f32x4*)(qc + qo + 4);
#pragma unroll
        for (int sl = 1; sl < 4; ++sl) {
          s0 += *(const f32x4*)(qc + sl * QSTR + qo);
          s1 += *(const f32x4*)(qc + sl * QSTR + qo + 4);
        }
        float sv[8];
        *(f32x4*)&sv[0] = s0;
        *(f32x4*)&sv[4] = s1;
#pragma unroll
        for (int j = 0; j < 8; ++j) {
          unsigned short hi = f2bf(sv[j]);
          qh[mi][j] = (short)hi;
          ql[mi][j] = (short)f2bf(sv[j] - bf2f(hi));
        }
      }
#pragma unroll
      for (int ni = 0; ni < 4; ++ni) {
        size_t ko = (size_t)(ni * 16 + fr) * 64 + kk * 32 + fq * 8;
        bf16x8 kh = *(const bf16x8*)(khb + ko);
        bf16x8 kl = *(const bf16x8*)(klb + ko);
#pragma unroll
        for (int mi = 0; mi < 2; ++mi) {
          sacc[mi][ni] = __builtin_amdgcn_mfma_f32_16x16x32_bf16(
              qh[mi], kh, sacc[mi][ni], 0, 0, 0);
          sacc[mi][ni] = __builtin_amdgcn_mfma_f32_16x16x32_bf16(
              qh[mi], kl, sacc[mi][ni], 0, 0, 0);
          sacc[mi][ni] = __builtin_amdgcn_mfma_f32_16x16x32_bf16(
              ql[mi], kh, sacc[mi][ni], 0, 0, 0);
        }
      }
    }

#pragma unroll
    for (int mi = 0; mi < 2; ++mi) {
#pragma unroll
      for (int r = 0; r < 4; ++r) {
        float m = fmaxf(fmaxf(sacc[mi][0][r], sacc[mi][1][r]),
                        fmaxf(sacc[mi][2][r], sacc[mi][3][r]));
#pragma unroll
        for (int o = 1; o < 16; o <<= 1) m = fmaxf(m, __shfl_xor(m, o));
        float e0 = __expf(sacc[mi][0][r] - m);
        float e1 = __expf(sacc[mi][1][r] - m);
        float e2 = __expf(sacc[mi][2][r] - m);
        float e3 = __expf(sacc[mi][3][r] - m);
        float s = e0 + e1 + e2 + e3;
#pragma unroll
        for (int o = 1; o < 16; o <<= 1) s += __shfl_xor(s, o);
        float inv = 1.f / s;
        int row = mi * 16 + fq * 4 + r;
        Pl[wid][row][fr] = f2bf(e0 * inv);
        Pl[wid][row][16 + fr] = f2bf(e1 * inv);
        Pl[wid][row][32 + fr] = f2bf(e2 * inv);
        Pl[wid][row][48 + fr] = f2bf(e3 * inv);
      }
    }

    f32x4 oacc[2][4];
#pragma unroll
    for (int i = 0; i < 2; ++i)
#pragma unroll
      for (int j = 0; j < 4; ++j) oacc[i][j] = (f32x4){0.f, 0.f, 0.f, 0.f};
#pragma unroll
    for (int kk = 0; kk < 2; ++kk) {
      bf16x8 pa[2];
#pragma unroll
      for (int mi = 0; mi < 2; ++mi)
        pa[mi] = *(const bf16x8*)&Pl[wid][mi * 16 + fr][kk * 32 + fq * 8];
#pragma unroll
      for (int ni = 0; ni < 4; ++ni) {
        bf16x8 vb = *(const bf16x8*)(vtb + (size_t)(ni * 16 + fr) * 64 +
                                     kk * 32 + fq * 8);
#pragma unroll
        for (int mi = 0; mi < 2; ++mi)
          oacc[mi][ni] = __builtin_amdgcn_mfma_f32_16x16x32_bf16(
              pa[mi], vb, oacc[mi][ni], 0, 0, 0);
      }
    }

#pragma unroll
    for (int mi = 0; mi < 2; ++mi)
#pragma unroll
      for (int r = 0; r < 4; ++r) {
        int row = mi * 16 + fq * 4 + r;
        if (rbase + row < n) {
          unsigned short* ar = attnc + (size_t)(qbase + row) * 512 + h * 64 + fr;
          ar[0] = f2bf(oacc[mi][0][r]);
          ar[16] = f2bf(oacc[mi][1][r]);
          ar[32] = f2bf(oacc[mi][2][r]);
          ar[48] = f2bf(oacc[mi][3][r]);
        }
      }
  }
}

// ---------- launch ----------
extern "C" void kernel_launch(void* const* d_in, const int* in_sizes, int n_in,
                              void* d_out, int out_size, void* d_ws,
                              size_t ws_size, hipStream_t stream) {
  const float* latent = (const float*)d_in[0];
  const float* y = (const float*)d_in[1];
  const int* mask = (const int*)d_in[2];
  const float* W_vk = (const float*)d_in[3];
  const float* W_q = (const float*)d_in[4];
  const float* W_out = (const float*)d_in[5];
  float* out = (float*)d_out;

  char* ws = (char*)d_ws;
  size_t off = 0;
  auto alloc = [&](size_t bytes) -> void* {
    void* p = ws + off;
    off = (off + bytes + 255) & ~(size_t)255;
    return p;
  };
  unsigned short* WqT_h = (unsigned short*)alloc((size_t)512 * 4096 * 2);
  unsigned short* WvkT_h = (unsigned short*)alloc((size_t)1024 * 2048 * 2);
  unsigned short* WvkT_l = (unsigned short*)alloc((size_t)1024 * 2048 * 2);
  unsigned short* WoT_h = (unsigned short*)alloc((size_t)4096 * 512 * 2);
  unsigned short* ybf = (unsigned short*)alloc((size_t)8192 * 4096 * 2);
  unsigned short* latbf = (unsigned short*)alloc((size_t)768 * 2048 * 2);
  float* qc = (float*)alloc((size_t)4 * QCAP * 512 * 4);   // 4 q slices
  float* kvp = (float*)alloc((size_t)8 * 768 * 1024 * 4);  // 8 kv slices
  unsigned short* Khb = (unsigned short*)alloc((size_t)768 * 512 * 2);
  unsigned short* Klb = (unsigned short*)alloc((size_t)768 * 512 * 2);
  unsigned short* Vtb = (unsigned short*)alloc((size_t)768 * 512 * 2);
  unsigned short* attnc = (unsigned short*)alloc((size_t)8192 * 512 * 2);
  int* cnt = (int*)alloc(12 * 4);
  int* idx = (int*)alloc((size_t)12 * 2048 * 4);
  int* offs = (int*)alloc(13 * 4);
  int* glob = (int*)alloc(8192 * 4);
  int* mcnt = (int*)alloc(4);
  int* mlist = (int*)alloc(8192 * 4);

  hipMemsetAsync(cnt, 0, 12 * 4, stream);
  hipMemsetAsync(mcnt, 0, 4, stream);

  // weights transpose + latent convert + mask gather (one dispatch)
  prep_fused<<<6944, 256, 0, stream>>>(W_q, W_vk, W_out, latent, mask, WqT_h,
                                       WvkT_h, WvkT_l, WoT_h, latbf, cnt, idx,
                                       mcnt, mlist);
  scan_build<<<12, 256, 0, stream>>>(cnt, offs, idx, glob);
  cvt_gather<<<16384, 256, 0, stream>>>(y, glob, offs, ybf);

  // kv partials (8 slices) + q partials (4 slices) in ONE dispatch
  gemm_dual<<<KVB + 1024, 256, 0, stream>>>(latbf, WvkT_h, WvkT_l, ybf, WqT_h,
                                            kvp, qc, offs);
  kv_finish<<<768, 256, 0, stream>>>(kvp, Khb, Klb, Vtb);
  // MFMA attention (sums 4 q partials)
  attn5<<<12 * 64, 256, 0, stream>>>(qc, Khb, Klb, Vtb, cnt, offs, attnc);
  // out = attnc[compact,512] @ W_out -> scatter; dead blocks zero-fill
  gemm_out<<<(8192 / BM) * (4096 / BN), 256, 0, stream>>>(
      attnc, WoT_h, out, glob, offs, mcnt, mlist, 8192, 4096, 512);
}

// Round 17
// 275.430 us; speedup vs baseline: 1.0845x; 1.0096x over previous
//
#include <hip/hip_runtime.h>
#include <hip/hip_bf16.h>

typedef __attribute__((ext_vector_type(4))) float f32x4;
typedef __attribute__((ext_vector_type(8))) short bf16x8;
typedef __attribute__((ext_vector_type(4))) unsigned short u16x4;
typedef __attribute__((ext_vector_type(8))) unsigned short u16x8;

#define QCAP 8256  // compact q buffer row capacity
#define QSTR ((size_t)QCAP * 512)
#define KVB 384    // kv blocks in gemm_dual: 6 bm x 8 bn x 4 ks x 2 part

__device__ __forceinline__ unsigned short f2bf(float f) {
  unsigned int u = __builtin_bit_cast(unsigned int, f);
  unsigned int r = (u + 0x7FFFu + ((u >> 16) & 1u)) >> 16;
  return (unsigned short)r;
}
__device__ __forceinline__ float bf2f(unsigned short h) {
  unsigned int u = ((unsigned int)h) << 16;
  return __builtin_bit_cast(float, u);
}

__device__ __forceinline__ void gload_lds16(const void* g, void* l) {
  __builtin_amdgcn_global_load_lds(
      (__attribute__((address_space(1))) unsigned int*)g,
      (__attribute__((address_space(3))) unsigned int*)l, 16, 0, 0);
}

// ---------- gather rows by (b, t); also collect masked rows ----------
__global__ __launch_bounds__(256) void gather_rows(const int* __restrict__ mask,
                                                   int* __restrict__ cnt,
                                                   int* __restrict__ idx,
                                                   int* __restrict__ mcnt,
                                                   int* __restrict__ mlist) {
  int g = blockIdx.x * 256 + threadIdx.x;
  int m = mask[g];
  if (m > 0) {
    int bt = (g >> 11) * 3 + m - 1;
    int p = atomicAdd(&cnt[bt], 1);
    idx[bt * 2048 + p] = g;
  } else {
    int p = atomicAdd(mcnt, 1);
    mlist[p] = g;
  }
}

// ---------- scan (local) + build bucket-major compact list ----------
__global__ __launch_bounds__(256) void scan_build(const int* __restrict__ cnt,
                                                  int* __restrict__ offs,
                                                  const int* __restrict__ idx,
                                                  int* __restrict__ glob) {
  __shared__ int so[13];
  if (threadIdx.x == 0) {
    int s = 0;
#pragma unroll
    for (int i = 0; i < 12; ++i) {
      so[i] = s;
      s += cnt[i];
    }
    so[12] = s;
    if (blockIdx.x == 0)
#pragma unroll
      for (int i = 0; i < 13; ++i) offs[i] = so[i];
  }
  __syncthreads();
  int bt = blockIdx.x;
  int n = cnt[bt], o = so[bt];
  for (int j = threadIdx.x; j < n; j += 256) glob[o + j] = idx[bt * 2048 + j];
}

// ---------- fused prep: y-gather-convert + weight transposes + latent ------
// bid [0,16384): cvt_gather y rows; [16384,22528): weight transposes;
// [22528,23296): latent convert. All independent; overlaps the streams.
__global__ __launch_bounds__(256) void prep_all(
    const float* __restrict__ y, const int* __restrict__ glob,
    const int* __restrict__ offs, unsigned short* __restrict__ ybf,
    const float* __restrict__ Wq, const float* __restrict__ Wvk,
    const float* __restrict__ Wo, const float* __restrict__ latent,
    unsigned short* __restrict__ QTh, unsigned short* __restrict__ VKh,
    unsigned short* __restrict__ VKl, unsigned short* __restrict__ OTh,
    unsigned short* __restrict__ latbf) {
  int bid = blockIdx.x;
  if (bid < 16384) {  // y gather + convert (compact valid rows)
    int p = bid >> 1, half = bid & 1;
    if (p >= offs[12]) return;
    int g = glob[p];
    const float* src = y + (size_t)g * 4096 + half * 2048 + threadIdx.x * 8;
    unsigned short* dst = ybf + (size_t)p * 4096 + half * 2048 + threadIdx.x * 8;
    f32x4 a = *(const f32x4*)src;
    f32x4 b = *(const f32x4*)(src + 4);
    u16x8 o;
#pragma unroll
    for (int j = 0; j < 4; ++j) o[j] = f2bf(a[j]);
#pragma unroll
    for (int j = 0; j < 4; ++j) o[4 + j] = f2bf(b[j]);
    *(u16x8*)dst = o;
    return;
  }
  if (bid >= 22528) {  // latent convert
    long i = ((long)(bid - 22528) * 256 + threadIdx.x) * 8;
    f32x4 a = *(const f32x4*)(latent + i);
    f32x4 b = *(const f32x4*)(latent + i + 4);
    u16x8 o;
#pragma unroll
    for (int j = 0; j < 4; ++j) o[j] = f2bf(a[j]);
#pragma unroll
    for (int j = 0; j < 4; ++j) o[4 + j] = f2bf(b[j]);
    *(u16x8*)(latbf + i) = o;
    return;
  }
  // weight transpose + (W_vk only) hi/lo split
  int wb = bid - 16384;
  __shared__ float tile[32][33];
  const float* W;
  unsigned short *Th, *Tl;
  int K, N, nbx, b;
  if (wb < 2048) {
    W = Wq; Th = QTh; Tl = nullptr; K = 4096; N = 512; nbx = 16; b = wb;
  } else if (wb < 4096) {
    W = Wvk; Th = VKh; Tl = VKl; K = 2048; N = 1024; nbx = 32; b = wb - 2048;
  } else {
    W = Wo; Th = OTh; Tl = nullptr; K = 512; N = 4096; nbx = 128; b = wb - 4096;
  }
  int n0 = (b % nbx) * 32, k0 = (b / nbx) * 32;
  int tx = threadIdx.x & 31, ty = threadIdx.x >> 5;
#pragma unroll
  for (int r = 0; r < 4; ++r)
    tile[ty + 8 * r][tx] = W[(size_t)(k0 + ty + 8 * r) * N + n0 + tx];
  __syncthreads();
#pragma unroll
  for (int r = 0; r < 4; ++r) {
    float f = tile[tx][ty + 8 * r];
    unsigned short hi = f2bf(f);
    size_t o = (size_t)(n0 + ty + 8 * r) * K + k0 + tx;
    Th[o] = hi;
    if (Tl) Tl[o] = f2bf(f - bf2f(hi));
  }
}

// ---------- kv finish: sum 8 partial slices (4 ks x 2 hi/lo parts) ----------
__global__ __launch_bounds__(256) void kv_finish(const float* __restrict__ kvp,
                                                 unsigned short* __restrict__ Kh,
                                                 unsigned short* __restrict__ Kl,
                                                 unsigned short* __restrict__ Vt) {
  int row = blockIdx.x;  // 0..767
  int bt = row >> 6, key = row & 63;
  int c = threadIdx.x * 4;
  const float* p = kvp + (size_t)row * 1024 + c;
  f32x4 v = *(const f32x4*)p;
#pragma unroll
  for (int sl = 1; sl < 8; ++sl)
    v += *(const f32x4*)(p + (size_t)sl * 768 * 1024);
  if (c < 512) {
    int h = c >> 6, d = c & 63;
    u16x4 hv, lv;
#pragma unroll
    for (int j = 0; j < 4; ++j) {
      unsigned short hi = f2bf(v[j]);
      hv[j] = hi;
      lv[j] = f2bf(v[j] - bf2f(hi));
    }
    size_t o = ((size_t)(bt * 8 + h) * 64 + key) * 64 + d;
    *(u16x4*)&Kh[o] = hv;
    *(u16x4*)&Kl[o] = lv;
  } else {
    int cc = c - 512;
    int h = cc >> 6, d = cc & 63;
#pragma unroll
    for (int j = 0; j < 4; ++j)
      Vt[((size_t)(bt * 8 + h) * 64 + d + j) * 64 + key] = f2bf(v[j]);
  }
}

#define BM 128
#define BN 128
#define BK 64

// ---------- combined kv + q GEMM (single dispatch, single-B, 32.9KB LDS) ----
__global__ __launch_bounds__(256) void gemm_dual(
    const unsigned short* __restrict__ latbf, const unsigned short* __restrict__ VKh,
    const unsigned short* __restrict__ VKl, const unsigned short* __restrict__ ybf,
    const unsigned short* __restrict__ QTh, float* __restrict__ kvp,
    float* __restrict__ qc, const int* __restrict__ offs) {
  __shared__ unsigned short smem[BM * BK + BN * BK + 64];
  unsigned short* Ald = smem;
  unsigned short* Bhld = smem + BM * BK;
  float* epi = (float*)smem;

  int tid = threadIdx.x, lane = tid & 63, wid = tid >> 6;
  int wr = wid >> 1, wc = wid & 1;
  const unsigned short *Ab, *Bb;
  float* Cv;
  int N, K, kbeg, kend, bm, bn;
  size_t outOff;
  if (blockIdx.x < KVB) {
    int w = (blockIdx.x & 7) * (KVB >> 3) + (blockIdx.x >> 3);  // XCD swizzle
    bm = w / 64;
    int r = w % 64;
    bn = r >> 3;
    int slice = r & 7, ks = slice & 3;
    Ab = latbf + (size_t)(bm * BM) * 2048;
    Bb = (slice < 4 ? VKh : VKl) + (size_t)(bn * BN) * 2048;
    Cv = kvp;
    N = 1024;
    K = 2048;
    kbeg = ks * 512;
    kend = kbeg + 512;
    outOff = (size_t)slice * 768 * 1024;
  } else {
    int qb = blockIdx.x - KVB;
    int w = (qb & 7) * 128 + (qb >> 3);  // XCD swizzle over 1024
    bm = w & 63;                         // bm fastest: dead tiles interleave
    int r = w >> 6;
    bn = r >> 2;
    int ks = r & 3;
    if (bm * BM >= offs[12]) return;  // compacted-away tile
    Ab = ybf + (size_t)(bm * BM) * 4096;
    Bb = QTh + (size_t)(bn * BN) * 4096;
    Cv = qc;
    N = 512;
    K = 4096;
    kbeg = ks * 1024;
    kend = kbeg + 1024;
    outOff = (size_t)ks * QSTR;
  }

  int fr = lane & 15, fq = lane >> 4;
  int srow = lane >> 3, scol = ((lane & 7) ^ (lane >> 3)) * 8;  // pre-swizzled

  f32x4 acc[4][4];
#pragma unroll
  for (int i = 0; i < 4; ++i)
#pragma unroll
    for (int j = 0; j < 4; ++j) acc[i][j] = (f32x4){0.f, 0.f, 0.f, 0.f};

  for (int k0 = kbeg; k0 < kend; k0 += BK) {
#pragma unroll
    for (int i = 0; i < 4; ++i) {
      int c = wid * 4 + i;
      size_t go = (size_t)(c * 8 + srow) * K + k0 + scol;
      gload_lds16(Ab + go, &Ald[c * 512]);
      gload_lds16(Bb + go, &Bhld[c * 512]);
    }
    __syncthreads();
#pragma unroll
    for (int kk = 0; kk < 2; ++kk) {
      int ca = (kk * 32 + fq * 8) ^ ((fr & 7) * 8);  // swizzled read col
      bf16x8 af[4], bf[4];
#pragma unroll
      for (int i = 0; i < 4; ++i) {
        af[i] = *(const bf16x8*)&Ald[(wr * 64 + i * 16 + fr) * BK + ca];
        bf[i] = *(const bf16x8*)&Bhld[(wc * 64 + i * 16 + fr) * BK + ca];
      }
#pragma unroll
      for (int mi = 0; mi < 4; ++mi)
#pragma unroll
        for (int ni = 0; ni < 4; ++ni)
          acc[mi][ni] = __builtin_amdgcn_mfma_f32_16x16x32_bf16(
              af[mi], bf[ni], acc[mi][ni], 0, 0, 0);
    }
    __syncthreads();
  }

  // LDS-reshape epilogue: 512B-contiguous stores
#pragma unroll 1
  for (int p = 0; p < 2; ++p) {
    __syncthreads();
    if (wr == p) {
#pragma unroll
      for (int mi = 0; mi < 4; ++mi)
#pragma unroll
        for (int ni = 0; ni < 4; ++ni)
#pragma unroll
          for (int r = 0; r < 4; ++r) {
            int lrow = mi * 16 + fq * 4 + r;
            int lcol = wc * 64 + ni * 16 + fr;
            int pc = lcol ^ ((lrow & 7) << 4);
            epi[lrow * 128 + pc] = acc[mi][ni][r];
          }
    }
    __syncthreads();
#pragma unroll
    for (int k = 0; k < 8; ++k) {
      int chunk = k * 256 + tid;
      int lrow = chunk >> 5;
      int c4 = (chunk & 31) * 4;
      int pc4 = c4 ^ ((lrow & 7) << 4);
      f32x4 v = *(f32x4*)&epi[lrow * 128 + pc4];
      int row = bm * BM + p * 64 + lrow;
      *(f32x4*)&Cv[outOff + (size_t)row * N + bn * BN + c4] = v;
    }
  }
}

// ---------- out-GEMM: bf16 single-B, row-scatter, fused zerofill ----------
__global__ __launch_bounds__(256) void gemm_out(
    const unsigned short* __restrict__ A, const unsigned short* __restrict__ Bh,
    float* __restrict__ Cv, const int* __restrict__ glob,
    const int* __restrict__ offs, const int* __restrict__ mcnt,
    const int* __restrict__ mlist, int M, int N, int K) {
  __shared__ unsigned short smem[BM * BK + BN * BK + 64];
  unsigned short* Ald = smem;
  unsigned short* Bhld = smem + BM * BK;
  float* epi = (float*)smem;

  int tid = threadIdx.x, lane = tid & 63, wid = tid >> 6;
  int wr = wid >> 1, wc = wid & 1;
  int nwg = gridDim.x;
  int w = (blockIdx.x & 7) * (nwg >> 3) + (blockIdx.x >> 3);
  int nTN = N / BN;
  int nBM = M / BM;
  int bm = w % nBM;
  int bn = w / nBM;
  int mv = offs[12];

  if (bm * BM >= mv) {
    // dead block: zero-fill masked output rows
    int bmLive = (mv + BM - 1) / BM;
    int nDead = (nBM - bmLive) * nTN;
    int deadIdx = (bm - bmLive) + bn * (nBM - bmLive);
    int nm = *mcnt;
    f32x4 z = (f32x4){0.f, 0.f, 0.f, 0.f};
    for (int j = deadIdx; j < nm; j += nDead) {
      float* row = Cv + (size_t)mlist[j] * N;
#pragma unroll
      for (int i = 0; i < 4; ++i) *(f32x4*)&row[(i * 256 + tid) * 4] = z;
    }
    return;
  }

  const unsigned short* Ab = A + (size_t)(bm * BM) * K;
  const unsigned short* Bhb = Bh + (size_t)(bn * BN) * K;
  int fr = lane & 15, fq = lane >> 4;
  int srow = lane >> 3, scol = ((lane & 7) ^ (lane >> 3)) * 8;

  f32x4 acc[4][4];
#pragma unroll
  for (int i = 0; i < 4; ++i)
#pragma unroll
    for (int j = 0; j < 4; ++j) acc[i][j] = (f32x4){0.f, 0.f, 0.f, 0.f};

  for (int k0 = 0; k0 < K; k0 += BK) {
#pragma unroll
    for (int i = 0; i < 4; ++i) {
      int c = wid * 4 + i;
      size_t go = (size_t)(c * 8 + srow) * K + k0 + scol;
      gload_lds16(Ab + go, &Ald[c * 512]);
      gload_lds16(Bhb + go, &Bhld[c * 512]);
    }
    __syncthreads();
#pragma unroll
    for (int kk = 0; kk < 2; ++kk) {
      int ca = (kk * 32 + fq * 8) ^ ((fr & 7) * 8);
      bf16x8 af[4], bf[4];
#pragma unroll
      for (int i = 0; i < 4; ++i) {
        af[i] = *(const bf16x8*)&Ald[(wr * 64 + i * 16 + fr) * BK + ca];
        bf[i] = *(const bf16x8*)&Bhld[(wc * 64 + i * 16 + fr) * BK + ca];
      }
#pragma unroll
      for (int mi = 0; mi < 4; ++mi)
#pragma unroll
        for (int ni = 0; ni < 4; ++ni)
          acc[mi][ni] = __builtin_amdgcn_mfma_f32_16x16x32_bf16(
              af[mi], bf[ni], acc[mi][ni], 0, 0, 0);
    }
    __syncthreads();
  }

#pragma unroll 1
  for (int p = 0; p < 2; ++p) {
    __syncthreads();
    if (wr == p) {
#pragma unroll
      for (int mi = 0; mi < 4; ++mi)
#pragma unroll
        for (int ni = 0; ni < 4; ++ni)
#pragma unroll
          for (int r = 0; r < 4; ++r) {
            int lrow = mi * 16 + fq * 4 + r;
            int lcol = wc * 64 + ni * 16 + fr;
            int pc = lcol ^ ((lrow & 7) << 4);
            epi[lrow * 128 + pc] = acc[mi][ni][r];
          }
    }
    __syncthreads();
#pragma unroll
    for (int k = 0; k < 8; ++k) {
      int chunk = k * 256 + tid;
      int lrow = chunk >> 5;
      int c4 = (chunk & 31) * 4;
      int pc4 = c4 ^ ((lrow & 7) << 4);
      f32x4 v = *(f32x4*)&epi[lrow * 128 + pc4];
      int row = bm * BM + p * 64 + lrow;
      if (row < mv)
        *(f32x4*)&Cv[(size_t)glob[row] * N + bn * BN + c4] = v;
    }
  }

  // rare fallback: masked rows exist but no dead blocks
  int bmLive = (mv + BM - 1) / BM;
  if (bmLive == nBM && bm == 0) {
    int nm = *mcnt;
    f32x4 z = (f32x4){0.f, 0.f, 0.f, 0.f};
    for (int j = bn; j < nm; j += nTN) {
      float* row = Cv + (size_t)mlist[j] * N;
#pragma unroll
      for (int i = 0; i < 4; ++i) *(f32x4*)&row[(i * 256 + tid) * 4] = z;
    }
  }
}

// ---------- MFMA attention (compact positions, sums 4 q partials) ----------
__global__ __launch_bounds__(256) void attn5(
    const float* __restrict__ qc, const unsigned short* __restrict__ Kh,
    const unsigned short* __restrict__ Kl, const unsigned short* __restrict__ Vt,
    const int* __restrict__ cnt, const int* __restrict__ offs,
    unsigned short* __restrict__ attnc) {
  __shared__ unsigned short Pl[4][32][72];
  int tid = threadIdx.x, wid = tid >> 6, lane = tid & 63;
  int fr = lane & 15, fq = lane >> 4;
  int bt = blockIdx.x >> 6, rt = blockIdx.x & 63;
  int n = cnt[bt];
  int rbase = rt * 32;
  if (rbase >= n) return;
  int qbase = offs[bt] + rbase;

#pragma unroll 1
  for (int hp = 0; hp < 2; ++hp) {
    int h = wid * 2 + hp;
    const unsigned short* khb = Kh + ((size_t)(bt * 8 + h) * 64) * 64;
    const unsigned short* klb = Kl + ((size_t)(bt * 8 + h) * 64) * 64;
    const unsigned short* vtb = Vt + ((size_t)(bt * 8 + h) * 64) * 64;

    f32x4 sacc[2][4];
#pragma unroll
    for (int i = 0; i < 2; ++i)
#pragma unroll
      for (int j = 0; j < 4; ++j) sacc[i][j] = (f32x4){0.f, 0.f, 0.f, 0.f};

#pragma unroll
    for (int kk = 0; kk < 2; ++kk) {
      bf16x8 qh[2], ql[2];
#pragma unroll
      for (int mi = 0; mi < 2; ++mi) {
        size_t qo = (size_t)(qbase + mi * 16 + fr) * 512 + h * 64 + kk * 32 + fq * 8;
        f32x4 s0 = *(const f32x4*)(qc + qo);
        f32x4 s1 = *(const f32x4*)(qc + qo + 4);
#pragma unroll
        for (int sl = 1; sl < 4; ++sl) {
          s0 += *(const f32x4*)(qc + sl * QSTR + qo);
          s1 += *(const f32x4*)(qc + sl * QSTR + qo + 4);
        }
        float sv[8];
        *(f32x4*)&sv[0] = s0;
        *(f32x4*)&sv[4] = s1;
#pragma unroll
        for (int j = 0; j < 8; ++j) {
          unsigned short hi = f2bf(sv[j]);
          qh[mi][j] = (short)hi;
          ql[mi][j] = (short)f2bf(sv[j] - bf2f(hi));
        }
      }
#pragma unroll
      for (int ni = 0; ni < 4; ++ni) {
        size_t ko = (size_t)(ni * 16 + fr) * 64 + kk * 32 + fq * 8;
        bf16x8 kh = *(const bf16x8*)(khb + ko);
        bf16x8 kl = *(const bf16x8*)(klb + ko);
#pragma unroll
        for (int mi = 0; mi < 2; ++mi) {
          sacc[mi][ni] = __builtin_amdgcn_mfma_f32_16x16x32_bf16(
              qh[mi], kh, sacc[mi][ni], 0, 0, 0);
          sacc[mi][ni] = __builtin_amdgcn_mfma_f32_16x16x32_bf16(
              qh[mi], kl, sacc[mi][ni], 0, 0, 0);
          sacc[mi][ni] = __builtin_amdgcn_mfma_f32_16x16x32_bf16(
              ql[mi], kh, sacc[mi][ni], 0, 0, 0);
        }
      }
    }

#pragma unroll
    for (int mi = 0; mi < 2; ++mi) {
#pragma unroll
      for (int r = 0; r < 4; ++r) {
        float m = fmaxf(fmaxf(sacc[mi][0][r], sacc[mi][1][r]),
                        fmaxf(sacc[mi][2][r], sacc[mi][3][r]));
#pragma unroll
        for (int o = 1; o < 16; o <<= 1) m = fmaxf(m, __shfl_xor(m, o));
        float e0 = __expf(sacc[mi][0][r] - m);
        float e1 = __expf(sacc[mi][1][r] - m);
        float e2 = __expf(sacc[mi][2][r] - m);
        float e3 = __expf(sacc[mi][3][r] - m);
        float s = e0 + e1 + e2 + e3;
#pragma unroll
        for (int o = 1; o < 16; o <<= 1) s += __shfl_xor(s, o);
        float inv = 1.f / s;
        int row = mi * 16 + fq * 4 + r;
        Pl[wid][row][fr] = f2bf(e0 * inv);
        Pl[wid][row][16 + fr] = f2bf(e1 * inv);
        Pl[wid][row][32 + fr] = f2bf(e2 * inv);
        Pl[wid][row][48 + fr] = f2bf(e3 * inv);
      }
    }

    f32x4 oacc[2][4];
#pragma unroll
    for (int i = 0; i < 2; ++i)
#pragma unroll
      for (int j = 0; j < 4; ++j) oacc[i][j] = (f32x4){0.f, 0.f, 0.f, 0.f};
#pragma unroll
    for (int kk = 0; kk < 2; ++kk) {
      bf16x8 pa[2];
#pragma unroll
      for (int mi = 0; mi < 2; ++mi)
        pa[mi] = *(const bf16x8*)&Pl[wid][mi * 16 + fr][kk * 32 + fq * 8];
#pragma unroll
      for (int ni = 0; ni < 4; ++ni) {
        bf16x8 vb = *(const bf16x8*)(vtb + (size_t)(ni * 16 + fr) * 64 +
                                     kk * 32 + fq * 8);
#pragma unroll
        for (int mi = 0; mi < 2; ++mi)
          oacc[mi][ni] = __builtin_amdgcn_mfma_f32_16x16x32_bf16(
              pa[mi], vb, oacc[mi][ni], 0, 0, 0);
      }
    }

#pragma unroll
    for (int mi = 0; mi < 2; ++mi)
#pragma unroll
      for (int r = 0; r < 4; ++r) {
        int row = mi * 16 + fq * 4 + r;
        if (rbase + row < n) {
          unsigned short* ar = attnc + (size_t)(qbase + row) * 512 + h * 64 + fr;
          ar[0] = f2bf(oacc[mi][0][r]);
          ar[16] = f2bf(oacc[mi][1][r]);
          ar[32] = f2bf(oacc[mi][2][r]);
          ar[48] = f2bf(oacc[mi][3][r]);
        }
      }
  }
}

// ---------- launch ----------
extern "C" void kernel_launch(void* const* d_in, const int* in_sizes, int n_in,
                              void* d_out, int out_size, void* d_ws,
                              size_t ws_size, hipStream_t stream) {
  const float* latent = (const float*)d_in[0];
  const float* y = (const float*)d_in[1];
  const int* mask = (const int*)d_in[2];
  const float* W_vk = (const float*)d_in[3];
  const float* W_q = (const float*)d_in[4];
  const float* W_out = (const float*)d_in[5];
  float* out = (float*)d_out;

  char* ws = (char*)d_ws;
  size_t off = 0;
  auto alloc = [&](size_t bytes) -> void* {
    void* p = ws + off;
    off = (off + bytes + 255) & ~(size_t)255;
    return p;
  };
  unsigned short* WqT_h = (unsigned short*)alloc((size_t)512 * 4096 * 2);
  unsigned short* WvkT_h = (unsigned short*)alloc((size_t)1024 * 2048 * 2);
  unsigned short* WvkT_l = (unsigned short*)alloc((size_t)1024 * 2048 * 2);
  unsigned short* WoT_h = (unsigned short*)alloc((size_t)4096 * 512 * 2);
  unsigned short* ybf = (unsigned short*)alloc((size_t)8192 * 4096 * 2);
  unsigned short* latbf = (unsigned short*)alloc((size_t)768 * 2048 * 2);
  float* qc = (float*)alloc((size_t)4 * QCAP * 512 * 4);   // 4 q slices
  float* kvp = (float*)alloc((size_t)8 * 768 * 1024 * 4);  // 8 kv slices
  unsigned short* Khb = (unsigned short*)alloc((size_t)768 * 512 * 2);
  unsigned short* Klb = (unsigned short*)alloc((size_t)768 * 512 * 2);
  unsigned short* Vtb = (unsigned short*)alloc((size_t)768 * 512 * 2);
  unsigned short* attnc = (unsigned short*)alloc((size_t)8192 * 512 * 2);
  int* cntm = (int*)alloc(13 * 4);  // cnt[12] + mcnt contiguous: 1 memset
  int* cnt = cntm;
  int* mcnt = cntm + 12;
  int* idx = (int*)alloc((size_t)12 * 2048 * 4);
  int* offs = (int*)alloc(13 * 4);
  int* glob = (int*)alloc(8192 * 4);
  int* mlist = (int*)alloc(8192 * 4);

  hipMemsetAsync(cntm, 0, 13 * 4, stream);

  gather_rows<<<32, 256, 0, stream>>>(mask, cnt, idx, mcnt, mlist);
  scan_build<<<12, 256, 0, stream>>>(cnt, offs, idx, glob);

  // y gather-convert + weight transposes + latent convert (one dispatch,
  // streams overlap)
  prep_all<<<23296, 256, 0, stream>>>(y, glob, offs, ybf, W_q, W_vk, W_out,
                                      latent, WqT_h, WvkT_h, WvkT_l, WoT_h,
                                      latbf);

  // kv partials (8 slices) + q partials (4 slices) in ONE dispatch
  gemm_dual<<<KVB + 1024, 256, 0, stream>>>(latbf, WvkT_h, WvkT_l, ybf, WqT_h,
                                            kvp, qc, offs);
  kv_finish<<<768, 256, 0, stream>>>(kvp, Khb, Klb, Vtb);
  // MFMA attention (sums 4 q partials)
  attn5<<<12 * 64, 256, 0, stream>>>(qc, Khb, Klb, Vtb, cnt, offs, attnc);
  // out = attnc[compact,512] @ W_out -> scatter; dead blocks zero-fill
  gemm_out<<<(8192 / BM) * (4096 / BN), 256, 0, stream>>>(
      attnc, WoT_h, out, glob, offs, mcnt, mlist, 8192, 4096, 512);
}